// Round 2
// baseline (395.630 us; speedup 1.0000x reference)
//
#include <hip/hip_runtime.h>
#include <hip/hip_bf16.h>
#include <stdint.h>

typedef __hip_bfloat16 bf16;
typedef __attribute__((ext_vector_type(8))) short bf16x8;
typedef __attribute__((ext_vector_type(4))) float f32x4;

#define B_   2
#define S_   2048
#define HID_ 2048
#define H_   32
#define KV_  8
#define D_   64

__device__ __forceinline__ void gload_lds16(const void* g, void* l) {
  __builtin_amdgcn_global_load_lds(
      (const __attribute__((address_space(1))) uint32_t*)g,
      (__attribute__((address_space(3))) uint32_t*)l, 16, 0, 0);
}

// f32 -> bf16 elementwise (RN), vectorized 4/thread, grid-stride.
__global__ __launch_bounds__(256) void cvt_f32_bf16(
    const float* __restrict__ s, bf16* __restrict__ d, int n4) {
  int i = blockIdx.x * blockDim.x + threadIdx.x;
  const int stride = gridDim.x * blockDim.x;
  for (; i < n4; i += stride) {
    float4 v = ((const float4*)s)[i];
    bf16 t[4];
    t[0] = __float2bfloat16(v.x);
    t[1] = __float2bfloat16(v.y);
    t[2] = __float2bfloat16(v.z);
    t[3] = __float2bfloat16(v.w);
    *reinterpret_cast<uint64_t*>(d + 4 * (size_t)i) = *reinterpret_cast<uint64_t*>(t);
  }
}

// C = A @ W^T + bias.   A:[M,K] bf16 row-major, W:[N,K] bf16 row-major, bias f32.
// MODE 0: C[m*N+n] (OutT=float)
// MODE 1: m=b*S_+s, n=h*64+d -> C[((b*Hn + h)*S_ + s)*64 + d]  (OutT=bf16 scatter)
template <int MODE, typename OutT>
__global__ __launch_bounds__(256, 2) void gemm_nt(
    const bf16* __restrict__ A, const bf16* __restrict__ W,
    const float* __restrict__ bias, OutT* __restrict__ C,
    int M, int N, int K, int Hn) {
  __shared__ __align__(16) bf16 As[128 * 64];
  __shared__ __align__(16) bf16 Bs[128 * 64];
  const int tid = threadIdx.x;
  const int lane = tid & 63, wid = tid >> 6;
  const int wr = wid >> 1, wc = wid & 1;
  const int bm = blockIdx.x, bn = blockIdx.y;

  f32x4 acc[4][4] = {};

  for (int k0 = 0; k0 < K; k0 += 64) {
    __syncthreads();
    // stage A,B tiles: linear LDS dest, pre-swizzled global source (G21)
#pragma unroll
    for (int c = 0; c < 4; ++c) {
      const int r = c * 32 + wid * 8 + (lane >> 3);
      const int gcolb = ((lane & 7) * 16) ^ ((r & 7) << 4);  // byte col, swizzled
      gload_lds16(A + (size_t)(bm * 128 + r) * K + k0 + (gcolb >> 1),
                  &As[(c * 32 + wid * 8) * 64]);
      gload_lds16(W + (size_t)(bn * 128 + r) * K + k0 + (gcolb >> 1),
                  &Bs[(c * 32 + wid * 8) * 64]);
    }
    __syncthreads();
#pragma unroll
    for (int ks = 0; ks < 2; ++ks) {
      bf16x8 af[4], bfr[4];
#pragma unroll
      for (int i = 0; i < 4; ++i) {
        const int ra = wr * 64 + i * 16 + (lane & 15);
        const int ka = (ks * 64 + ((lane >> 4) << 4)) ^ ((ra & 7) << 4);
        af[i] = *(const bf16x8*)((const char*)As + ra * 128 + ka);
        const int rb = wc * 64 + i * 16 + (lane & 15);
        const int kb = (ks * 64 + ((lane >> 4) << 4)) ^ ((rb & 7) << 4);
        bfr[i] = *(const bf16x8*)((const char*)Bs + rb * 128 + kb);
      }
#pragma unroll
      for (int i = 0; i < 4; ++i)
#pragma unroll
        for (int j = 0; j < 4; ++j)
          acc[i][j] = __builtin_amdgcn_mfma_f32_16x16x32_bf16(af[i], bfr[j], acc[i][j], 0, 0, 0);
    }
  }

  // epilogue: C/D layout col=lane&15, row=(lane>>4)*4+e  (m89)
#pragma unroll
  for (int j = 0; j < 4; ++j) {
    const int n = bn * 128 + wc * 64 + j * 16 + (lane & 15);
    const float bv = bias[n];
#pragma unroll
    for (int i = 0; i < 4; ++i) {
      const int mb = bm * 128 + wr * 64 + i * 16 + ((lane >> 4) << 2);
#pragma unroll
      for (int e = 0; e < 4; ++e) {
        const int m = mb + e;
        const float v = acc[i][j][e] + bv;
        if constexpr (MODE == 0) {
          C[(size_t)m * N + n] = v;
        } else {
          const int b = m >> 11, s = m & (S_ - 1);
          const int h = n >> 6, d = n & 63;
          C[(((size_t)b * Hn + h) * S_ + s) * 64 + d] = __float2bfloat16(v);
        }
      }
    }
  }
}

// Flash attention: q:[B,H,S,D], k/v:[B,KV,S,D] bf16, mask:[B,S] f32 additive on keys.
// out: [B,S,H*D] bf16. Block = (qtile 64 rows) x (one b,h). 4 waves, 16 q-rows/wave.
__global__ __launch_bounds__(256, 2) void attn_fwd(
    const bf16* __restrict__ qb, const bf16* __restrict__ kb,
    const bf16* __restrict__ vb, const float* __restrict__ mask,
    bf16* __restrict__ ob) {
  const int qtile = blockIdx.x;   // 0..31
  const int headid = blockIdx.y;  // 0..63 = b*H_+h
  const int b = headid >> 5, h = headid & (H_ - 1);
  const int kv = h >> 2;  // G=4
  const int tid = threadIdx.x, lane = tid & 63, wid = tid >> 6;

  __shared__ __align__(16) bf16 Ks[64 * 64];
  __shared__ __align__(16) bf16 VTs[64 * 64];   // V transposed: VT[d][key], swizzled
  __shared__ __align__(16) bf16 Ps[4][16 * 64]; // per-wave P, swizzled

  const bf16* qh = qb + ((size_t)(b * H_ + h) * S_) * D_;
  const bf16* kh = kb + ((size_t)(b * KV_ + kv) * S_) * D_;
  const bf16* vh = vb + ((size_t)(b * KV_ + kv) * S_) * D_;
  const float* mrow = mask + (size_t)b * S_;

  // hoist Q fragments (A-frag: row=lane&15, k=(lane>>4)*8)
  const int qrow = qtile * 64 + wid * 16 + (lane & 15);
  bf16x8 qf[2];
  qf[0] = *(const bf16x8*)(qh + (size_t)qrow * D_ + ((lane >> 4) * 8));
  qf[1] = *(const bf16x8*)(qh + (size_t)qrow * D_ + 32 + ((lane >> 4) * 8));

  float m_i[4], l_i[4];
  f32x4 o[4];
#pragma unroll
  for (int e = 0; e < 4; ++e) { m_i[e] = -1e30f; l_i[e] = 0.f; }
#pragma unroll
  for (int j = 0; j < 4; ++j) o[j] = f32x4{0.f, 0.f, 0.f, 0.f};

  char* PsW = (char*)&Ps[wid][0];

  for (int t = 0; t < S_ / 64; ++t) {
    __syncthreads();
    // stage K tile [64 keys][64 d], swizzled source + linear LDS
#pragma unroll
    for (int c = 0; c < 2; ++c) {
      const int r = c * 32 + wid * 8 + (lane >> 3);
      const int gcolb = ((lane & 7) * 16) ^ ((r & 7) << 4);
      gload_lds16(kh + ((size_t)t * 64 + r) * D_ + (gcolb >> 1),
                  &Ks[(c * 32 + wid * 8) * 64]);
    }
    // stage V transposed: thread(lane=key, wid=d-block); swizzled scalar writes
    {
      const int key = lane;
      const bf16* vp = vh + ((size_t)t * 64 + key) * D_ + wid * 16;
      bf16x8 v0 = *(const bf16x8*)(vp);
      bf16x8 v1 = *(const bf16x8*)(vp + 8);
#pragma unroll
      for (int j2 = 0; j2 < 8; ++j2) {
        const int d0 = wid * 16 + j2;
        *(short*)((char*)VTs + d0 * 128 + ((key * 2) ^ ((d0 & 7) << 4))) = v0[j2];
        const int d1 = wid * 16 + 8 + j2;
        *(short*)((char*)VTs + d1 * 128 + ((key * 2) ^ ((d1 & 7) << 4))) = v1[j2];
      }
    }
    __syncthreads();

    // QK^T: s[f] covers keys f*16..f*16+15
    f32x4 s[4];
#pragma unroll
    for (int f = 0; f < 4; ++f) s[f] = f32x4{0.f, 0.f, 0.f, 0.f};
#pragma unroll
    for (int ks = 0; ks < 2; ++ks) {
#pragma unroll
      for (int f = 0; f < 4; ++f) {
        const int rk = f * 16 + (lane & 15);
        const int kbyte = (ks * 64 + ((lane >> 4) << 4)) ^ ((rk & 7) << 4);
        bf16x8 kf = *(const bf16x8*)((const char*)Ks + rk * 128 + kbyte);
        s[f] = __builtin_amdgcn_mfma_f32_16x16x32_bf16(qf[ks], kf, s[f], 0, 0, 0);
      }
    }

    // scale + mask; online softmax (16-lane groups share rows)
    float pv_[4][4];
#pragma unroll
    for (int f = 0; f < 4; ++f) {
      const float mk = mrow[t * 64 + f * 16 + (lane & 15)];
#pragma unroll
      for (int e = 0; e < 4; ++e) pv_[f][e] = s[f][e] * 0.125f + mk;
    }
#pragma unroll
    for (int e = 0; e < 4; ++e) {
      float mx = fmaxf(fmaxf(pv_[0][e], pv_[1][e]), fmaxf(pv_[2][e], pv_[3][e]));
      mx = fmaxf(mx, __shfl_xor(mx, 1));
      mx = fmaxf(mx, __shfl_xor(mx, 2));
      mx = fmaxf(mx, __shfl_xor(mx, 4));
      mx = fmaxf(mx, __shfl_xor(mx, 8));
      const float mn = fmaxf(m_i[e], mx);
      const float alpha = __expf(m_i[e] - mn);
      m_i[e] = mn;
      float rs = 0.f;
      const int r = ((lane >> 4) << 2) + e;
#pragma unroll
      for (int f = 0; f < 4; ++f) {
        const float p = __expf(pv_[f][e] - mn);
        rs += p;
        const int col = f * 16 + (lane & 15);
        *(bf16*)(PsW + r * 128 + ((col * 2) ^ ((r & 7) << 4))) = __float2bfloat16(p);
      }
      rs += __shfl_xor(rs, 1);
      rs += __shfl_xor(rs, 2);
      rs += __shfl_xor(rs, 4);
      rs += __shfl_xor(rs, 8);
      l_i[e] = l_i[e] * alpha + rs;
#pragma unroll
      for (int j = 0; j < 4; ++j) o[j][e] *= alpha;
    }

    // PV: o[j] += P @ V  (A from Ps, B from VTs)
#pragma unroll
    for (int ks = 0; ks < 2; ++ks) {
      const int ra = lane & 15;
      const int kbyte = (ks * 64 + ((lane >> 4) << 4)) ^ ((ra & 7) << 4);
      bf16x8 pa = *(const bf16x8*)(PsW + ra * 128 + kbyte);
#pragma unroll
      for (int j = 0; j < 4; ++j) {
        const int rd = j * 16 + (lane & 15);
        const int kb2 = (ks * 64 + ((lane >> 4) << 4)) ^ ((rd & 7) << 4);
        bf16x8 vf = *(const bf16x8*)((const char*)VTs + rd * 128 + kb2);
        o[j] = __builtin_amdgcn_mfma_f32_16x16x32_bf16(pa, vf, o[j], 0, 0, 0);
      }
    }
  }

  // write out to [B,S,H*D]
#pragma unroll
  for (int j = 0; j < 4; ++j) {
    const int d = j * 16 + (lane & 15);
#pragma unroll
    for (int e = 0; e < 4; ++e) {
      const int srow = qtile * 64 + wid * 16 + ((lane >> 4) << 2) + e;
      const float val = o[j][e] / l_i[e];
      ob[((size_t)b * S_ + srow) * HID_ + h * 64 + d] = __float2bfloat16(val);
    }
  }
}

extern "C" void kernel_launch(void* const* d_in, const int* in_sizes, int n_in,
                              void* d_out, int out_size, void* d_ws, size_t ws_size,
                              hipStream_t stream) {
  (void)in_sizes; (void)n_in; (void)out_size; (void)ws_size;
  const float* x  = (const float*)d_in[0];
  const float* am = (const float*)d_in[1];
  const float* Wq = (const float*)d_in[2];
  const float* bq = (const float*)d_in[3];
  const float* Wk = (const float*)d_in[4];
  const float* bk = (const float*)d_in[5];
  const float* Wv = (const float*)d_in[6];
  const float* bv = (const float*)d_in[7];
  const float* Wo = (const float*)d_in[8];
  const float* bo = (const float*)d_in[9];
  float* out = (float*)d_out;

  const size_t XE  = (size_t)B_ * S_ * HID_;      // 8.39M
  const size_t WQE = (size_t)HID_ * HID_;         // 4.19M
  const size_t WKE = (size_t)(KV_ * D_) * HID_;   // 1.05M
  const size_t QE  = (size_t)B_ * H_ * S_ * D_;   // 8.39M
  const size_t KE  = (size_t)B_ * KV_ * S_ * D_;  // 2.1M

  bf16* xb  = (bf16*)d_ws;
  bf16* wqb = xb + XE;
  bf16* wkb = wqb + WQE;
  bf16* wvb = wkb + WKE;
  bf16* wob = wvb + WKE;
  bf16* qbuf = wob + WQE;
  bf16* kbuf = qbuf + QE;
  bf16* vbuf = kbuf + KE;
  bf16* abuf = vbuf + KE;   // [B,S,HID] bf16

  dim3 blk(256);
  // f32 -> bf16 conversions
  cvt_f32_bf16<<<2048, blk, 0, stream>>>(x,  xb,  (int)(XE / 4));
  cvt_f32_bf16<<<2048, blk, 0, stream>>>(Wq, wqb, (int)(WQE / 4));
  cvt_f32_bf16<<<1024, blk, 0, stream>>>(Wk, wkb, (int)(WKE / 4));
  cvt_f32_bf16<<<1024, blk, 0, stream>>>(Wv, wvb, (int)(WKE / 4));
  cvt_f32_bf16<<<2048, blk, 0, stream>>>(Wo, wob, (int)(WQE / 4));

  const int M = B_ * S_;  // 4096
  gemm_nt<1, bf16><<<dim3(M / 128, HID_ / 128), blk, 0, stream>>>(xb, wqb, bq, qbuf, M, HID_, HID_, H_);
  gemm_nt<1, bf16><<<dim3(M / 128, (KV_ * D_) / 128), blk, 0, stream>>>(xb, wkb, bk, kbuf, M, KV_ * D_, HID_, KV_);
  gemm_nt<1, bf16><<<dim3(M / 128, (KV_ * D_) / 128), blk, 0, stream>>>(xb, wvb, bv, vbuf, M, KV_ * D_, HID_, KV_);
  attn_fwd<<<dim3(S_ / 64, B_ * H_), blk, 0, stream>>>(qbuf, kbuf, vbuf, am, abuf);
  gemm_nt<0, float><<<dim3(M / 128, HID_ / 128), blk, 0, stream>>>(abuf, wob, bo, out, M, HID_, HID_, 0);
}

// Round 3
// 253.841 us; speedup vs baseline: 1.5586x; 1.5586x over previous
//
#include <hip/hip_runtime.h>
#include <hip/hip_bf16.h>
#include <stdint.h>

typedef __hip_bfloat16 bf16;
typedef __attribute__((ext_vector_type(8))) short bf16x8;
typedef __attribute__((ext_vector_type(4))) float f32x4;

#define B_   2
#define S_   2048
#define HID_ 2048
#define H_   32
#define KV_  8
#define D_   64
#define NT_  (S_ / 64)
#define LOG2E 1.4426950408889634f

__device__ __forceinline__ void gload_lds16(const void* g, void* l) {
  __builtin_amdgcn_global_load_lds(
      (const __attribute__((address_space(1))) uint32_t*)g,
      (__attribute__((address_space(3))) uint32_t*)l, 16, 0, 0);
}
__device__ __forceinline__ float fexp2(float x) { return __builtin_amdgcn_exp2f(x); }

// f32 -> bf16 elementwise (RN), vectorized 4/thread, grid-stride.
__global__ __launch_bounds__(256) void cvt_f32_bf16(
    const float* __restrict__ s, bf16* __restrict__ d, int n4) {
  int i = blockIdx.x * blockDim.x + threadIdx.x;
  const int stride = gridDim.x * blockDim.x;
  for (; i < n4; i += stride) {
    float4 v = ((const float4*)s)[i];
    bf16 t[4];
    t[0] = __float2bfloat16(v.x);
    t[1] = __float2bfloat16(v.y);
    t[2] = __float2bfloat16(v.z);
    t[3] = __float2bfloat16(v.w);
    *reinterpret_cast<uint64_t*>(d + 4 * (size_t)i) = *reinterpret_cast<uint64_t*>(t);
  }
}

// ---------------- fused QKV projection: C = A @ W^T + b, head-major scatter ----
__global__ __launch_bounds__(256, 2) void gemm_qkv(
    const bf16* __restrict__ A,
    const bf16* __restrict__ Wqp, const bf16* __restrict__ Wkp, const bf16* __restrict__ Wvp,
    const float* __restrict__ bqp, const float* __restrict__ bkp, const float* __restrict__ bvp,
    bf16* __restrict__ Cq, bf16* __restrict__ Ck, bf16* __restrict__ Cv) {
  const int bn_all = blockIdx.y;
  const bf16* W; const float* bias; bf16* C; int Hn; int bn;
  if (bn_all < 16)      { W = Wqp; bias = bqp; C = Cq; Hn = H_;  bn = bn_all; }
  else if (bn_all < 20) { W = Wkp; bias = bkp; C = Ck; Hn = KV_; bn = bn_all - 16; }
  else                  { W = Wvp; bias = bvp; C = Cv; Hn = KV_; bn = bn_all - 20; }

  __shared__ __align__(16) bf16 As[128 * 64];
  __shared__ __align__(16) bf16 Bs[128 * 64];
  const int tid = threadIdx.x;
  const int lane = tid & 63, wid = tid >> 6;
  const int wr = wid >> 1, wc = wid & 1;
  const int bm = blockIdx.x;
  const int K = HID_;

  f32x4 acc[4][4] = {};

  for (int k0 = 0; k0 < K; k0 += 64) {
    __syncthreads();
#pragma unroll
    for (int c = 0; c < 4; ++c) {
      const int r = c * 32 + wid * 8 + (lane >> 3);
      const int gcolb = ((lane & 7) * 16) ^ ((r & 7) << 4);
      gload_lds16(A + (size_t)(bm * 128 + r) * K + k0 + (gcolb >> 1),
                  &As[(c * 32 + wid * 8) * 64]);
      gload_lds16(W + (size_t)(bn * 128 + r) * K + k0 + (gcolb >> 1),
                  &Bs[(c * 32 + wid * 8) * 64]);
    }
    __syncthreads();
#pragma unroll
    for (int ks = 0; ks < 2; ++ks) {
      bf16x8 af[4], bfr[4];
#pragma unroll
      for (int i = 0; i < 4; ++i) {
        const int ra = wr * 64 + i * 16 + (lane & 15);
        const int ka = (ks * 64 + ((lane >> 4) << 4)) ^ ((ra & 7) << 4);
        af[i] = *(const bf16x8*)((const char*)As + ra * 128 + ka);
        const int rb = wc * 64 + i * 16 + (lane & 15);
        const int kb = (ks * 64 + ((lane >> 4) << 4)) ^ ((rb & 7) << 4);
        bfr[i] = *(const bf16x8*)((const char*)Bs + rb * 128 + kb);
      }
      __builtin_amdgcn_s_setprio(1);
#pragma unroll
      for (int i = 0; i < 4; ++i)
#pragma unroll
        for (int j = 0; j < 4; ++j)
          acc[i][j] = __builtin_amdgcn_mfma_f32_16x16x32_bf16(af[i], bfr[j], acc[i][j], 0, 0, 0);
      __builtin_amdgcn_s_setprio(0);
    }
  }

#pragma unroll
  for (int j = 0; j < 4; ++j) {
    const int n = bn * 128 + wc * 64 + j * 16 + (lane & 15);
    const float bv = bias[n];
#pragma unroll
    for (int i = 0; i < 4; ++i) {
      const int mb = bm * 128 + wr * 64 + i * 16 + ((lane >> 4) << 2);
#pragma unroll
      for (int e = 0; e < 4; ++e) {
        const int m = mb + e;
        const float v = acc[i][j][e] + bv;
        const int b = m >> 11, s = m & (S_ - 1);
        const int h = n >> 6, d = n & 63;
        C[(((size_t)b * Hn + h) * S_ + s) * 64 + d] = __float2bfloat16(v);
      }
    }
  }
}

// ---------------- output projection: out = A @ Wo^T + bo (f32 out) -------------
__global__ __launch_bounds__(256, 2) void gemm_out(
    const bf16* __restrict__ A, const bf16* __restrict__ W,
    const float* __restrict__ bias, float* __restrict__ C) {
  __shared__ __align__(16) bf16 As[128 * 64];
  __shared__ __align__(16) bf16 Bs[128 * 64];
  const int tid = threadIdx.x;
  const int lane = tid & 63, wid = tid >> 6;
  const int wr = wid >> 1, wc = wid & 1;
  const int bm = blockIdx.x, bn = blockIdx.y;
  const int K = HID_, N = HID_;

  f32x4 acc[4][4] = {};

  for (int k0 = 0; k0 < K; k0 += 64) {
    __syncthreads();
#pragma unroll
    for (int c = 0; c < 4; ++c) {
      const int r = c * 32 + wid * 8 + (lane >> 3);
      const int gcolb = ((lane & 7) * 16) ^ ((r & 7) << 4);
      gload_lds16(A + (size_t)(bm * 128 + r) * K + k0 + (gcolb >> 1),
                  &As[(c * 32 + wid * 8) * 64]);
      gload_lds16(W + (size_t)(bn * 128 + r) * K + k0 + (gcolb >> 1),
                  &Bs[(c * 32 + wid * 8) * 64]);
    }
    __syncthreads();
#pragma unroll
    for (int ks = 0; ks < 2; ++ks) {
      bf16x8 af[4], bfr[4];
#pragma unroll
      for (int i = 0; i < 4; ++i) {
        const int ra = wr * 64 + i * 16 + (lane & 15);
        const int ka = (ks * 64 + ((lane >> 4) << 4)) ^ ((ra & 7) << 4);
        af[i] = *(const bf16x8*)((const char*)As + ra * 128 + ka);
        const int rb = wc * 64 + i * 16 + (lane & 15);
        const int kb = (ks * 64 + ((lane >> 4) << 4)) ^ ((rb & 7) << 4);
        bfr[i] = *(const bf16x8*)((const char*)Bs + rb * 128 + kb);
      }
      __builtin_amdgcn_s_setprio(1);
#pragma unroll
      for (int i = 0; i < 4; ++i)
#pragma unroll
        for (int j = 0; j < 4; ++j)
          acc[i][j] = __builtin_amdgcn_mfma_f32_16x16x32_bf16(af[i], bfr[j], acc[i][j], 0, 0, 0);
      __builtin_amdgcn_s_setprio(0);
    }
  }

#pragma unroll
  for (int j = 0; j < 4; ++j) {
    const int n = bn * 128 + wc * 64 + j * 16 + (lane & 15);
    const float bv = bias[n];
#pragma unroll
    for (int i = 0; i < 4; ++i) {
      const int mb = bm * 128 + wr * 64 + i * 16 + ((lane >> 4) << 2);
#pragma unroll
      for (int e = 0; e < 4; ++e) {
        C[(size_t)(mb + e) * N + n] = acc[i][j][e] + bv;
      }
    }
  }
}

// ---------------- flash attention, pipelined + defer-max ----------------------
// q:[B,H,S,D], k/v:[B,KV,S,D] bf16, mask:[B,S] f32 additive. out:[B,S,H*D] bf16.
__global__ __launch_bounds__(256, 4) void attn_fwd(
    const bf16* __restrict__ qb, const bf16* __restrict__ kb,
    const bf16* __restrict__ vb, const float* __restrict__ mask,
    bf16* __restrict__ ob) {
  const int qtile = blockIdx.x;
  const int headid = blockIdx.y;
  const int b = headid >> 5, h = headid & (H_ - 1);
  const int kv = h >> 2;
  const int tid = threadIdx.x, lane = tid & 63, wid = tid >> 6;

  __shared__ __align__(16) bf16 Ks[2][64 * 64];
  __shared__ __align__(16) bf16 VTs[2][64 * 64];
  __shared__ __align__(16) bf16 Ps[4][16 * 64];

  const bf16* qh = qb + ((size_t)(b * H_ + h) * S_) * D_;
  const bf16* kh = kb + ((size_t)(b * KV_ + kv) * S_) * D_;
  const bf16* vh = vb + ((size_t)(b * KV_ + kv) * S_) * D_;
  const float* mrow = mask + (size_t)b * S_;

  const int qrow = qtile * 64 + wid * 16 + (lane & 15);
  bf16x8 qf[2];
  qf[0] = *(const bf16x8*)(qh + (size_t)qrow * D_ + ((lane >> 4) * 8));
  qf[1] = *(const bf16x8*)(qh + (size_t)qrow * D_ + 32 + ((lane >> 4) * 8));

  const float SL = 0.125f * LOG2E;

  float m_i[4], lp[4];
  f32x4 o[4];
#pragma unroll
  for (int e = 0; e < 4; ++e) { m_i[e] = 0.f; lp[e] = 0.f; }
#pragma unroll
  for (int j = 0; j < 4; ++j) o[j] = f32x4{0.f, 0.f, 0.f, 0.f};

  char* PsW = (char*)&Ps[wid][0];

  // ---- prologue: stage tile 0
#pragma unroll
  for (int c = 0; c < 2; ++c) {
    const int r = c * 32 + wid * 8 + (lane >> 3);
    const int gcolb = ((lane & 7) * 16) ^ ((r & 7) << 4);
    gload_lds16(kh + (size_t)r * D_ + (gcolb >> 1), &Ks[0][(c * 32 + wid * 8) * 64]);
  }
  bf16x8 vn0 = *(const bf16x8*)(vh + (size_t)lane * D_ + wid * 16);
  bf16x8 vn1 = *(const bf16x8*)(vh + (size_t)lane * D_ + wid * 16 + 8);
  {
    const int key2 = lane * 2;
#pragma unroll
    for (int j2 = 0; j2 < 8; ++j2) {
      const int d0 = wid * 16 + j2;
      *(short*)((char*)&VTs[0][0] + d0 * 128 + (key2 ^ ((d0 & 7) << 4))) = vn0[j2];
      const int d1 = d0 + 8;
      *(short*)((char*)&VTs[0][0] + d1 * 128 + (key2 ^ ((d1 & 7) << 4))) = vn1[j2];
    }
  }
  __syncthreads();

  for (int t = 0; t < NT_; ++t) {
    const int cur = t & 1, nxt = cur ^ 1;

    // ---- prefetch tile t+1 (lands during this compute phase)
    if (t < NT_ - 1) {
#pragma unroll
      for (int c = 0; c < 2; ++c) {
        const int r = c * 32 + wid * 8 + (lane >> 3);
        const int gcolb = ((lane & 7) * 16) ^ ((r & 7) << 4);
        gload_lds16(kh + ((size_t)(t + 1) * 64 + r) * D_ + (gcolb >> 1),
                    &Ks[nxt][(c * 32 + wid * 8) * 64]);
      }
      vn0 = *(const bf16x8*)(vh + ((size_t)(t + 1) * 64 + lane) * D_ + wid * 16);
      vn1 = *(const bf16x8*)(vh + ((size_t)(t + 1) * 64 + lane) * D_ + wid * 16 + 8);
    }

    // ---- QK^T
    f32x4 s[4];
#pragma unroll
    for (int f = 0; f < 4; ++f) s[f] = f32x4{0.f, 0.f, 0.f, 0.f};
#pragma unroll
    for (int ks = 0; ks < 2; ++ks) {
      bf16x8 kfr[4];
#pragma unroll
      for (int f = 0; f < 4; ++f) {
        const int rk = f * 16 + (lane & 15);
        const int kbyte = (ks * 64 + ((lane >> 4) << 4)) ^ ((rk & 7) << 4);
        kfr[f] = *(const bf16x8*)((const char*)&Ks[cur][0] + rk * 128 + kbyte);
      }
      __builtin_amdgcn_s_setprio(1);
#pragma unroll
      for (int f = 0; f < 4; ++f)
        s[f] = __builtin_amdgcn_mfma_f32_16x16x32_bf16(qf[ks], kfr[f], s[f], 0, 0, 0);
      __builtin_amdgcn_s_setprio(0);
    }

    // ---- softmax (defer-max: common path has zero cross-lane reductions)
    float pv_[4][4], p_[4][4];
#pragma unroll
    for (int f = 0; f < 4; ++f) {
      const float mkL = mrow[t * 64 + f * 16 + (lane & 15)] * LOG2E;
#pragma unroll
      for (int e = 0; e < 4; ++e) pv_[f][e] = s[f][e] * SL + mkL;
    }
#pragma unroll
    for (int f = 0; f < 4; ++f)
#pragma unroll
      for (int e = 0; e < 4; ++e) p_[f][e] = fexp2(pv_[f][e] - m_i[e]);

    float big = 0.f;
#pragma unroll
    for (int f = 0; f < 4; ++f)
#pragma unroll
      for (int e = 0; e < 4; ++e) big = fmaxf(big, p_[f][e]);

    if (t == 0 || __any(big > 256.0f)) {  // rare path: full online-softmax rescale
#pragma unroll
      for (int e = 0; e < 4; ++e) {
        float mx = fmaxf(fmaxf(pv_[0][e], pv_[1][e]), fmaxf(pv_[2][e], pv_[3][e]));
        mx = fmaxf(mx, __shfl_xor(mx, 1));
        mx = fmaxf(mx, __shfl_xor(mx, 2));
        mx = fmaxf(mx, __shfl_xor(mx, 4));
        mx = fmaxf(mx, __shfl_xor(mx, 8));
        const float mn = (t == 0) ? mx : fmaxf(m_i[e], mx);
        const float alpha = (t == 0) ? 0.f : fexp2(m_i[e] - mn);
        lp[e] *= alpha;
#pragma unroll
        for (int j = 0; j < 4; ++j) o[j][e] *= alpha;
        m_i[e] = mn;
      }
#pragma unroll
      for (int f = 0; f < 4; ++f)
#pragma unroll
        for (int e = 0; e < 4; ++e) p_[f][e] = fexp2(pv_[f][e] - m_i[e]);
    }

    // lane-local l accumulation (reduced once after the loop)
#pragma unroll
    for (int e = 0; e < 4; ++e)
      lp[e] += (p_[0][e] + p_[1][e]) + (p_[2][e] + p_[3][e]);

    // store P (bf16, swizzled, per-wave buffer)
#pragma unroll
    for (int e = 0; e < 4; ++e) {
      const int r = ((lane >> 4) << 2) + e;
#pragma unroll
      for (int f = 0; f < 4; ++f) {
        const int col2 = (f * 16 + (lane & 15)) * 2;
        *(bf16*)(PsW + r * 128 + (col2 ^ ((r & 7) << 4))) = __float2bfloat16(p_[f][e]);
      }
    }

    // ---- PV
#pragma unroll
    for (int ks = 0; ks < 2; ++ks) {
      const int ra = lane & 15;
      const int kbyte = (ks * 64 + ((lane >> 4) << 4)) ^ ((ra & 7) << 4);
      bf16x8 pa = *(const bf16x8*)(PsW + ra * 128 + kbyte);
      bf16x8 vfr[4];
#pragma unroll
      for (int j = 0; j < 4; ++j) {
        const int rd = j * 16 + (lane & 15);
        const int kb2 = (ks * 64 + ((lane >> 4) << 4)) ^ ((rd & 7) << 4);
        vfr[j] = *(const bf16x8*)((const char*)&VTs[cur][0] + rd * 128 + kb2);
      }
      __builtin_amdgcn_s_setprio(1);
#pragma unroll
      for (int j = 0; j < 4; ++j)
        o[j] = __builtin_amdgcn_mfma_f32_16x16x32_bf16(pa, vfr[j], o[j], 0, 0, 0);
      __builtin_amdgcn_s_setprio(0);
    }

    __syncthreads();  // all reads of [cur] and prefetch loads drained

    if (t < NT_ - 1) {  // write V^T(t+1) into the other buffer
      const int key2 = lane * 2;
#pragma unroll
      for (int j2 = 0; j2 < 8; ++j2) {
        const int d0 = wid * 16 + j2;
        *(short*)((char*)&VTs[nxt][0] + d0 * 128 + (key2 ^ ((d0 & 7) << 4))) = vn0[j2];
        const int d1 = d0 + 8;
        *(short*)((char*)&VTs[nxt][0] + d1 * 128 + (key2 ^ ((d1 & 7) << 4))) = vn1[j2];
      }
    }
    __syncthreads();  // next tile's K (gload) + V^T visible
  }

  // final l reduce (was per-tile before)
  float l_i[4];
#pragma unroll
  for (int e = 0; e < 4; ++e) {
    float r = lp[e];
    r += __shfl_xor(r, 1);
    r += __shfl_xor(r, 2);
    r += __shfl_xor(r, 4);
    r += __shfl_xor(r, 8);
    l_i[e] = r;
  }

#pragma unroll
  for (int j = 0; j < 4; ++j) {
    const int d = j * 16 + (lane & 15);
#pragma unroll
    for (int e = 0; e < 4; ++e) {
      const int srow = qtile * 64 + wid * 16 + ((lane >> 4) << 2) + e;
      const float val = o[j][e] / l_i[e];
      ob[((size_t)b * S_ + srow) * HID_ + h * 64 + d] = __float2bfloat16(val);
    }
  }
}

extern "C" void kernel_launch(void* const* d_in, const int* in_sizes, int n_in,
                              void* d_out, int out_size, void* d_ws, size_t ws_size,
                              hipStream_t stream) {
  (void)in_sizes; (void)n_in; (void)out_size; (void)ws_size;
  const float* x  = (const float*)d_in[0];
  const float* am = (const float*)d_in[1];
  const float* Wq = (const float*)d_in[2];
  const float* bq = (const float*)d_in[3];
  const float* Wk = (const float*)d_in[4];
  const float* bk = (const float*)d_in[5];
  const float* Wv = (const float*)d_in[6];
  const float* bv = (const float*)d_in[7];
  const float* Wo = (const float*)d_in[8];
  const float* bo = (const float*)d_in[9];
  float* out = (float*)d_out;

  const size_t XE  = (size_t)B_ * S_ * HID_;
  const size_t WQE = (size_t)HID_ * HID_;
  const size_t WKE = (size_t)(KV_ * D_) * HID_;
  const size_t QE  = (size_t)B_ * H_ * S_ * D_;
  const size_t KE  = (size_t)B_ * KV_ * S_ * D_;

  bf16* xb  = (bf16*)d_ws;
  bf16* wqb = xb + XE;
  bf16* wkb = wqb + WQE;
  bf16* wvb = wkb + WKE;
  bf16* wob = wvb + WKE;
  bf16* qbuf = wob + WQE;
  bf16* kbuf = qbuf + QE;
  bf16* vbuf = kbuf + KE;
  bf16* abuf = vbuf + KE;

  dim3 blk(256);
  cvt_f32_bf16<<<2048, blk, 0, stream>>>(x,  xb,  (int)(XE / 4));
  cvt_f32_bf16<<<2048, blk, 0, stream>>>(Wq, wqb, (int)(WQE / 4));
  cvt_f32_bf16<<<1024, blk, 0, stream>>>(Wk, wkb, (int)(WKE / 4));
  cvt_f32_bf16<<<1024, blk, 0, stream>>>(Wv, wvb, (int)(WKE / 4));
  cvt_f32_bf16<<<2048, blk, 0, stream>>>(Wo, wob, (int)(WQE / 4));

  const int M = B_ * S_;
  gemm_qkv<<<dim3(M / 128, 24), blk, 0, stream>>>(xb, wqb, wkb, wvb, bq, bk, bv,
                                                  qbuf, kbuf, vbuf);
  attn_fwd<<<dim3(S_ / 64, B_ * H_), blk, 0, stream>>>(qbuf, kbuf, vbuf, am, abuf);
  gemm_out<<<dim3(M / 128, HID_ / 128), blk, 0, stream>>>(abuf, wob, bo, out);
}

// Round 4
// 225.612 us; speedup vs baseline: 1.7536x; 1.1251x over previous
//
#include <hip/hip_runtime.h>
#include <hip/hip_bf16.h>
#include <stdint.h>

typedef __hip_bfloat16 bf16;
typedef __attribute__((ext_vector_type(8))) short bf16x8;
typedef __attribute__((ext_vector_type(4))) float f32x4;
typedef __attribute__((ext_vector_type(16))) float f32x16;
typedef __attribute__((ext_vector_type(4))) int i32x4;
typedef __attribute__((ext_vector_type(2))) int i32x2;

#define B_   2
#define S_   2048
#define HID_ 2048
#define H_   32
#define KV_  8
#define D_   64
#define NT_  (S_ / 64)
#define LOG2E 1.4426950408889634f

__device__ __forceinline__ void gload_lds16(const void* g, void* l) {
  __builtin_amdgcn_global_load_lds(
      (const __attribute__((address_space(1))) uint32_t*)g,
      (__attribute__((address_space(3))) uint32_t*)l, 16, 0, 0);
}
__device__ __forceinline__ float fexp2(float x) { return __builtin_amdgcn_exp2f(x); }

__device__ __forceinline__ uint32_t cvtpk_bf16(float lo, float hi) {
  uint32_t r;
  asm("v_cvt_pk_bf16_f32 %0, %1, %2" : "=v"(r) : "v"(lo), "v"(hi));
  return r;
}
// a' = {lanes<32: a} ∪ {lanes>=32: partner's b};  b' = {lanes<32: partner's a} ∪ {lanes>=32: b}
__device__ __forceinline__ void plane32_swap(uint32_t& a, uint32_t& b) {
  i32x2 r = __builtin_amdgcn_permlane32_swap((int)a, (int)b, false, false);
  a = (uint32_t)r[0]; b = (uint32_t)r[1];
}

// f32 -> bf16 elementwise (RN), vectorized 4/thread, grid-stride.
__global__ __launch_bounds__(256) void cvt_f32_bf16(
    const float* __restrict__ s, bf16* __restrict__ d, int n4) {
  int i = blockIdx.x * blockDim.x + threadIdx.x;
  const int stride = gridDim.x * blockDim.x;
  for (; i < n4; i += stride) {
    float4 v = ((const float4*)s)[i];
    bf16 t[4];
    t[0] = __float2bfloat16(v.x);
    t[1] = __float2bfloat16(v.y);
    t[2] = __float2bfloat16(v.z);
    t[3] = __float2bfloat16(v.w);
    *reinterpret_cast<uint64_t*>(d + 4 * (size_t)i) = *reinterpret_cast<uint64_t*>(t);
  }
}

// ---------------- fused QKV projection: C = A @ W^T + b, head-major scatter ----
__global__ __launch_bounds__(256, 2) void gemm_qkv(
    const bf16* __restrict__ A,
    const bf16* __restrict__ Wqp, const bf16* __restrict__ Wkp, const bf16* __restrict__ Wvp,
    const float* __restrict__ bqp, const float* __restrict__ bkp, const float* __restrict__ bvp,
    bf16* __restrict__ Cq, bf16* __restrict__ Ck, bf16* __restrict__ Cv) {
  const int bn_all = blockIdx.y;
  const bf16* W; const float* bias; bf16* C; int Hn; int bn;
  if (bn_all < 16)      { W = Wqp; bias = bqp; C = Cq; Hn = H_;  bn = bn_all; }
  else if (bn_all < 20) { W = Wkp; bias = bkp; C = Ck; Hn = KV_; bn = bn_all - 16; }
  else                  { W = Wvp; bias = bvp; C = Cv; Hn = KV_; bn = bn_all - 20; }

  __shared__ __align__(16) bf16 As[128 * 64];
  __shared__ __align__(16) bf16 Bs[128 * 64];
  const int tid = threadIdx.x;
  const int lane = tid & 63, wid = tid >> 6;
  const int wr = wid >> 1, wc = wid & 1;
  const int bm = blockIdx.x;
  const int K = HID_;

  f32x4 acc[4][4] = {};

  for (int k0 = 0; k0 < K; k0 += 64) {
    __syncthreads();
#pragma unroll
    for (int c = 0; c < 4; ++c) {
      const int r = c * 32 + wid * 8 + (lane >> 3);
      const int gcolb = ((lane & 7) * 16) ^ ((r & 7) << 4);
      gload_lds16(A + (size_t)(bm * 128 + r) * K + k0 + (gcolb >> 1),
                  &As[(c * 32 + wid * 8) * 64]);
      gload_lds16(W + (size_t)(bn * 128 + r) * K + k0 + (gcolb >> 1),
                  &Bs[(c * 32 + wid * 8) * 64]);
    }
    __syncthreads();
#pragma unroll
    for (int ks = 0; ks < 2; ++ks) {
      bf16x8 af[4], bfr[4];
#pragma unroll
      for (int i = 0; i < 4; ++i) {
        const int ra = wr * 64 + i * 16 + (lane & 15);
        const int ka = (ks * 64 + ((lane >> 4) << 4)) ^ ((ra & 7) << 4);
        af[i] = *(const bf16x8*)((const char*)As + ra * 128 + ka);
        const int rb = wc * 64 + i * 16 + (lane & 15);
        const int kb = (ks * 64 + ((lane >> 4) << 4)) ^ ((rb & 7) << 4);
        bfr[i] = *(const bf16x8*)((const char*)Bs + rb * 128 + kb);
      }
      __builtin_amdgcn_s_setprio(1);
#pragma unroll
      for (int i = 0; i < 4; ++i)
#pragma unroll
        for (int j = 0; j < 4; ++j)
          acc[i][j] = __builtin_amdgcn_mfma_f32_16x16x32_bf16(af[i], bfr[j], acc[i][j], 0, 0, 0);
      __builtin_amdgcn_s_setprio(0);
    }
  }

#pragma unroll
  for (int j = 0; j < 4; ++j) {
    const int n = bn * 128 + wc * 64 + j * 16 + (lane & 15);
    const float bv = bias[n];
#pragma unroll
    for (int i = 0; i < 4; ++i) {
      const int mb = bm * 128 + wr * 64 + i * 16 + ((lane >> 4) << 2);
#pragma unroll
      for (int e = 0; e < 4; ++e) {
        const int m = mb + e;
        const float v = acc[i][j][e] + bv;
        const int b = m >> 11, s = m & (S_ - 1);
        const int h = n >> 6, d = n & 63;
        C[(((size_t)b * Hn + h) * S_ + s) * 64 + d] = __float2bfloat16(v);
      }
    }
  }
}

// ---------------- output projection: out = A @ Wo^T + bo (f32 out) -------------
__global__ __launch_bounds__(256, 2) void gemm_out(
    const bf16* __restrict__ A, const bf16* __restrict__ W,
    const float* __restrict__ bias, float* __restrict__ C) {
  __shared__ __align__(16) bf16 As[128 * 64];
  __shared__ __align__(16) bf16 Bs[128 * 64];
  const int tid = threadIdx.x;
  const int lane = tid & 63, wid = tid >> 6;
  const int wr = wid >> 1, wc = wid & 1;
  const int bm = blockIdx.x, bn = blockIdx.y;
  const int K = HID_, N = HID_;

  f32x4 acc[4][4] = {};

  for (int k0 = 0; k0 < K; k0 += 64) {
    __syncthreads();
#pragma unroll
    for (int c = 0; c < 4; ++c) {
      const int r = c * 32 + wid * 8 + (lane >> 3);
      const int gcolb = ((lane & 7) * 16) ^ ((r & 7) << 4);
      gload_lds16(A + (size_t)(bm * 128 + r) * K + k0 + (gcolb >> 1),
                  &As[(c * 32 + wid * 8) * 64]);
      gload_lds16(W + (size_t)(bn * 128 + r) * K + k0 + (gcolb >> 1),
                  &Bs[(c * 32 + wid * 8) * 64]);
    }
    __syncthreads();
#pragma unroll
    for (int ks = 0; ks < 2; ++ks) {
      bf16x8 af[4], bfr[4];
#pragma unroll
      for (int i = 0; i < 4; ++i) {
        const int ra = wr * 64 + i * 16 + (lane & 15);
        const int ka = (ks * 64 + ((lane >> 4) << 4)) ^ ((ra & 7) << 4);
        af[i] = *(const bf16x8*)((const char*)As + ra * 128 + ka);
        const int rb = wc * 64 + i * 16 + (lane & 15);
        const int kb = (ks * 64 + ((lane >> 4) << 4)) ^ ((rb & 7) << 4);
        bfr[i] = *(const bf16x8*)((const char*)Bs + rb * 128 + kb);
      }
      __builtin_amdgcn_s_setprio(1);
#pragma unroll
      for (int i = 0; i < 4; ++i)
#pragma unroll
        for (int j = 0; j < 4; ++j)
          acc[i][j] = __builtin_amdgcn_mfma_f32_16x16x32_bf16(af[i], bfr[j], acc[i][j], 0, 0, 0);
      __builtin_amdgcn_s_setprio(0);
    }
  }

#pragma unroll
  for (int j = 0; j < 4; ++j) {
    const int n = bn * 128 + wc * 64 + j * 16 + (lane & 15);
    const float bv = bias[n];
#pragma unroll
    for (int i = 0; i < 4; ++i) {
      const int mb = bm * 128 + wr * 64 + i * 16 + ((lane >> 4) << 2);
#pragma unroll
      for (int e = 0; e < 4; ++e) {
        C[(size_t)(mb + e) * N + n] = acc[i][j][e] + bv;
      }
    }
  }
}

// ---------------- flash attention: 4 warps x 32 q-rows, swapped QK^T, 32x32 MFMA
// q:[B,H,S,D], k/v:[B,KV,S,D] bf16, mask:[B,S] f32 additive. out:[B,S,H*D] bf16.
// S^T = mfma32x32x16(A=K, B=Q): lane owns q = lane&31; per-lane 32 P values/tile.
// P -> bf16 A-frags in-register via v_cvt_pk_bf16_f32 + permlane32_swap (T12).
__global__ __launch_bounds__(256, 4) void attn_fwd(
    const bf16* __restrict__ qb, const bf16* __restrict__ kb,
    const bf16* __restrict__ vb, const float* __restrict__ mask,
    bf16* __restrict__ ob) {
  const int qtile = blockIdx.x;   // 0..15 (128 q-rows each)
  const int headid = blockIdx.y;  // 0..63
  const int b = headid >> 5, h = headid & (H_ - 1);
  const int kv = h >> 2;
  const int tid = threadIdx.x, lane = tid & 63, wid = tid >> 6;
  const int l31 = lane & 31, hi = lane >> 5;

  __shared__ __align__(16) bf16 Ks[2][64 * 64];
  __shared__ __align__(16) bf16 VTs[2][64 * 64];  // VT[d][key], swizzled
  __shared__ float lsm[4][32];

  const bf16* qh = qb + ((size_t)(b * H_ + h) * S_) * D_;
  const bf16* kh = kb + ((size_t)(b * KV_ + kv) * S_) * D_;
  const bf16* vh = vb + ((size_t)(b * KV_ + kv) * S_) * D_;
  const float* mrow = mask + (size_t)b * S_;

  // Q B-frags: B[k=d][n=q]: lane holds q=l31, d = ks*16 + hi*8 + j
  const int qrow = qtile * 128 + wid * 32 + l31;
  bf16x8 qf[4];
#pragma unroll
  for (int ks = 0; ks < 4; ++ks)
    qf[ks] = *(const bf16x8*)(qh + (size_t)qrow * D_ + ks * 16 + hi * 8);

  const float SL = 0.125f * LOG2E;
  float m_i = -1e30f, lp = 0.f;
  f32x16 o[2] = {};

  // ---- prologue: stage tile 0
#pragma unroll
  for (int c = 0; c < 2; ++c) {
    const int r = c * 32 + wid * 8 + (lane >> 3);
    const int gcolb = ((lane & 7) * 16) ^ ((r & 7) << 4);
    gload_lds16(kh + (size_t)r * D_ + (gcolb >> 1), &Ks[0][(c * 32 + wid * 8) * 64]);
  }
  bf16x8 vn0 = *(const bf16x8*)(vh + (size_t)lane * D_ + wid * 16);
  bf16x8 vn1 = *(const bf16x8*)(vh + (size_t)lane * D_ + wid * 16 + 8);
  {
    const int key2 = lane * 2;
#pragma unroll
    for (int j2 = 0; j2 < 8; ++j2) {
      const int d0 = wid * 16 + j2;
      *(short*)((char*)&VTs[0][0] + d0 * 128 + (key2 ^ ((d0 & 7) << 4))) = vn0[j2];
      const int d1 = d0 + 8;
      *(short*)((char*)&VTs[0][0] + d1 * 128 + (key2 ^ ((d1 & 7) << 4))) = vn1[j2];
    }
  }
  __syncthreads();

  for (int t = 0; t < NT_; ++t) {
    const int cur = t & 1, nxt = cur ^ 1;

    // ---- prefetch tile t+1
    if (t < NT_ - 1) {
#pragma unroll
      for (int c = 0; c < 2; ++c) {
        const int r = c * 32 + wid * 8 + (lane >> 3);
        const int gcolb = ((lane & 7) * 16) ^ ((r & 7) << 4);
        gload_lds16(kh + ((size_t)(t + 1) * 64 + r) * D_ + (gcolb >> 1),
                    &Ks[nxt][(c * 32 + wid * 8) * 64]);
      }
      vn0 = *(const bf16x8*)(vh + ((size_t)(t + 1) * 64 + lane) * D_ + wid * 16);
      vn1 = *(const bf16x8*)(vh + ((size_t)(t + 1) * 64 + lane) * D_ + wid * 16 + 8);
    }

    // ---- QK^T (swapped): s[kb] = S^T[key = kb*32 + rowpat][q = l31]
    f32x16 s[2] = {};
#pragma unroll
    for (int kbv = 0; kbv < 2; ++kbv) {
      __builtin_amdgcn_s_setprio(1);
#pragma unroll
      for (int ks = 0; ks < 4; ++ks) {
        const int rk = kbv * 32 + l31;
        const int kbyte = (ks * 32 + hi * 16) ^ ((rk & 7) << 4);
        bf16x8 kf = *(const bf16x8*)((const char*)&Ks[cur][0] + rk * 128 + kbyte);
        s[kbv] = __builtin_amdgcn_mfma_f32_32x32x16_bf16(kf, qf[ks], s[kbv], 0, 0, 0);
      }
      __builtin_amdgcn_s_setprio(0);
    }

    // ---- scale + mask (log2 domain): key(r,hi) = (r&3) + 8*(r>>2) + 4*hi
#pragma unroll
    for (int kbv = 0; kbv < 2; ++kbv) {
#pragma unroll
      for (int rq = 0; rq < 4; ++rq) {
        const f32x4 m4 = *(const f32x4*)(mrow + t * 64 + kbv * 32 + rq * 8 + 4 * hi);
#pragma unroll
        for (int e = 0; e < 4; ++e)
          s[kbv][rq * 4 + e] = s[kbv][rq * 4 + e] * SL + m4[e] * LOG2E;
      }
    }

    // ---- defer-max online softmax (lane-local row)
    float big = -1e30f;
#pragma unroll
    for (int kbv = 0; kbv < 2; ++kbv)
#pragma unroll
      for (int r = 0; r < 16; ++r) big = fmaxf(big, s[kbv][r]);
    {
      uint32_t ba = __float_as_uint(big), bb = ba;
      plane32_swap(ba, bb);
      big = fmaxf(__uint_as_float(ba), __uint_as_float(bb));  // pair max (q-row max)
    }
    if (__any(big > m_i + 8.f)) {  // rare: rescale (always at t=0)
      const float mnew = fmaxf(m_i, big);
      const float alpha = fexp2(m_i - mnew);
      m_i = mnew;
      lp *= alpha;
      lsm[wid][l31] = alpha;  // pair lanes write identical value
      asm volatile("s_waitcnt lgkmcnt(0)" ::: "memory");
#pragma unroll
      for (int rq = 0; rq < 4; ++rq) {
        const f32x4 a4 = *(const f32x4*)&lsm[wid][rq * 8 + 4 * hi];
#pragma unroll
        for (int e = 0; e < 4; ++e) {
          o[0][rq * 4 + e] *= a4[e];
          o[1][rq * 4 + e] *= a4[e];
        }
      }
    }
    // exp (in place) + lane-local l
    float psum = 0.f;
#pragma unroll
    for (int kbv = 0; kbv < 2; ++kbv)
#pragma unroll
      for (int r = 0; r < 16; ++r) {
        const float p = fexp2(s[kbv][r] - m_i);
        s[kbv][r] = p;
        psum += p;
      }
    lp += psum;

    // ---- build P A-frags: pa[kb][ks2], A[m=q=l31][k = kb*32 + ks2*16 + hi*8 + j]
    bf16x8 pa[2][2];
#pragma unroll
    for (int kbv = 0; kbv < 2; ++kbv) {
      uint32_t a0 = cvtpk_bf16(s[kbv][0], s[kbv][1]);
      uint32_t b0 = cvtpk_bf16(s[kbv][4], s[kbv][5]);
      plane32_swap(a0, b0);  // a0 = word0, b0 = word2
      uint32_t a1 = cvtpk_bf16(s[kbv][2], s[kbv][3]);
      uint32_t b1 = cvtpk_bf16(s[kbv][6], s[kbv][7]);
      plane32_swap(a1, b1);  // a1 = word1, b1 = word3
      i32x4 t0; t0[0] = (int)a0; t0[1] = (int)a1; t0[2] = (int)b0; t0[3] = (int)b1;
      pa[kbv][0] = __builtin_bit_cast(bf16x8, t0);
      uint32_t a2 = cvtpk_bf16(s[kbv][8], s[kbv][9]);
      uint32_t b2 = cvtpk_bf16(s[kbv][12], s[kbv][13]);
      plane32_swap(a2, b2);
      uint32_t a3 = cvtpk_bf16(s[kbv][10], s[kbv][11]);
      uint32_t b3 = cvtpk_bf16(s[kbv][14], s[kbv][15]);
      plane32_swap(a3, b3);
      i32x4 t1; t1[0] = (int)a2; t1[1] = (int)a3; t1[2] = (int)b2; t1[3] = (int)b3;
      pa[kbv][1] = __builtin_bit_cast(bf16x8, t1);
    }

    // ---- PV: o[db] += P @ V, B-frag from VT rows d = db*32 + l31
#pragma unroll
    for (int db = 0; db < 2; ++db) {
      __builtin_amdgcn_s_setprio(1);
#pragma unroll
      for (int kbv = 0; kbv < 2; ++kbv)
#pragma unroll
        for (int ks2 = 0; ks2 < 2; ++ks2) {
          const int rd = db * 32 + l31;
          const int vbyte = (kbv * 64 + ks2 * 32 + hi * 16) ^ ((rd & 7) << 4);
          bf16x8 vf = *(const bf16x8*)((const char*)&VTs[cur][0] + rd * 128 + vbyte);
          o[db] = __builtin_amdgcn_mfma_f32_32x32x16_bf16(pa[kbv][ks2], vf, o[db], 0, 0, 0);
        }
      __builtin_amdgcn_s_setprio(0);
    }

    __syncthreads();
    if (t < NT_ - 1) {
      const int key2 = lane * 2;
#pragma unroll
      for (int j2 = 0; j2 < 8; ++j2) {
        const int d0 = wid * 16 + j2;
        *(short*)((char*)&VTs[nxt][0] + d0 * 128 + (key2 ^ ((d0 & 7) << 4))) = vn0[j2];
        const int d1 = d0 + 8;
        *(short*)((char*)&VTs[nxt][0] + d1 * 128 + (key2 ^ ((d1 & 7) << 4))) = vn1[j2];
      }
    }
    __syncthreads();
  }

  // ---- epilogue: full row-sum l (pair add), redistribute to C/D layout, write
  {
    uint32_t la = __float_as_uint(lp), lb = la;
    plane32_swap(la, lb);
    const float lsum = __uint_as_float(la) + __uint_as_float(lb);
    lsm[wid][l31] = lsum;
  }
  __syncthreads();
#pragma unroll
  for (int rq = 0; rq < 4; ++rq) {
    const f32x4 l4 = *(const f32x4*)&lsm[wid][rq * 8 + 4 * hi];
#pragma unroll
    for (int e2 = 0; e2 < 4; ++e2) {
      const float inv = 1.0f / l4[e2];
      const int q_out = e2 + 8 * rq + 4 * hi;
      const int srow = qtile * 128 + wid * 32 + q_out;
#pragma unroll
      for (int db = 0; db < 2; ++db) {
        const float val = o[db][rq * 4 + e2] * inv;
        ob[((size_t)b * S_ + srow) * HID_ + h * 64 + db * 32 + l31] = __float2bfloat16(val);
      }
    }
  }
}

extern "C" void kernel_launch(void* const* d_in, const int* in_sizes, int n_in,
                              void* d_out, int out_size, void* d_ws, size_t ws_size,
                              hipStream_t stream) {
  (void)in_sizes; (void)n_in; (void)out_size; (void)ws_size;
  const float* x  = (const float*)d_in[0];
  const float* am = (const float*)d_in[1];
  const float* Wq = (const float*)d_in[2];
  const float* bq = (const float*)d_in[3];
  const float* Wk = (const float*)d_in[4];
  const float* bk = (const float*)d_in[5];
  const float* Wv = (const float*)d_in[6];
  const float* bv = (const float*)d_in[7];
  const float* Wo = (const float*)d_in[8];
  const float* bo = (const float*)d_in[9];
  float* out = (float*)d_out;

  const size_t XE  = (size_t)B_ * S_ * HID_;
  const size_t WQE = (size_t)HID_ * HID_;
  const size_t WKE = (size_t)(KV_ * D_) * HID_;
  const size_t QE  = (size_t)B_ * H_ * S_ * D_;
  const size_t KE  = (size_t)B_ * KV_ * S_ * D_;

  bf16* xb  = (bf16*)d_ws;
  bf16* wqb = xb + XE;
  bf16* wkb = wqb + WQE;
  bf16* wvb = wkb + WKE;
  bf16* wob = wvb + WKE;
  bf16* qbuf = wob + WQE;
  bf16* kbuf = qbuf + QE;
  bf16* vbuf = kbuf + KE;
  bf16* abuf = vbuf + KE;

  dim3 blk(256);
  cvt_f32_bf16<<<2048, blk, 0, stream>>>(x,  xb,  (int)(XE / 4));
  cvt_f32_bf16<<<2048, blk, 0, stream>>>(Wq, wqb, (int)(WQE / 4));
  cvt_f32_bf16<<<1024, blk, 0, stream>>>(Wk, wkb, (int)(WKE / 4));
  cvt_f32_bf16<<<1024, blk, 0, stream>>>(Wv, wvb, (int)(WKE / 4));
  cvt_f32_bf16<<<2048, blk, 0, stream>>>(Wo, wob, (int)(WQE / 4));

  const int M = B_ * S_;
  gemm_qkv<<<dim3(M / 128, 24), blk, 0, stream>>>(xb, wqb, wkb, wvb, bq, bk, bv,
                                                  qbuf, kbuf, vbuf);
  attn_fwd<<<dim3(S_ / 128, B_ * H_), blk, 0, stream>>>(qbuf, kbuf, vbuf, am, abuf);
  gemm_out<<<dim3(M / 128, HID_ / 128), blk, 0, stream>>>(abuf, wob, bo, out);
}

// Round 5
// 209.551 us; speedup vs baseline: 1.8880x; 1.0766x over previous
//
#include <hip/hip_runtime.h>
#include <hip/hip_bf16.h>
#include <stdint.h>

typedef __hip_bfloat16 bf16;
typedef __attribute__((ext_vector_type(8))) short bf16x8;
typedef __attribute__((ext_vector_type(4))) float f32x4;
typedef __attribute__((ext_vector_type(16))) float f32x16;
typedef __attribute__((ext_vector_type(4))) int i32x4;
typedef __attribute__((ext_vector_type(2))) int i32x2;

#define B_   2
#define S_   2048
#define HID_ 2048
#define H_   32
#define KV_  8
#define D_   64
#define NT_  (S_ / 64)
#define LOG2E 1.4426950408889634f

__device__ __forceinline__ void gload_lds16(const void* g, void* l) {
  __builtin_amdgcn_global_load_lds(
      (const __attribute__((address_space(1))) uint32_t*)g,
      (__attribute__((address_space(3))) uint32_t*)l, 16, 0, 0);
}
__device__ __forceinline__ float fexp2(float x) { return __builtin_amdgcn_exp2f(x); }

__device__ __forceinline__ uint32_t cvtpk_bf16(float lo, float hi) {
  uint32_t r;
  asm("v_cvt_pk_bf16_f32 %0, %1, %2" : "=v"(r) : "v"(lo), "v"(hi));
  return r;
}
__device__ __forceinline__ void plane32_swap(uint32_t& a, uint32_t& b) {
  i32x2 r = __builtin_amdgcn_permlane32_swap((int)a, (int)b, false, false);
  a = (uint32_t)r[0]; b = (uint32_t)r[1];
}

// f32 -> bf16 elementwise (RN), vectorized 4/thread, grid-stride.
__global__ __launch_bounds__(256) void cvt_f32_bf16(
    const float* __restrict__ s, bf16* __restrict__ d, int n4) {
  int i = blockIdx.x * blockDim.x + threadIdx.x;
  const int stride = gridDim.x * blockDim.x;
  for (; i < n4; i += stride) {
    float4 v = ((const float4*)s)[i];
    bf16 t[4];
    t[0] = __float2bfloat16(v.x);
    t[1] = __float2bfloat16(v.y);
    t[2] = __float2bfloat16(v.z);
    t[3] = __float2bfloat16(v.w);
    *reinterpret_cast<uint64_t*>(d + 4 * (size_t)i) = *reinterpret_cast<uint64_t*>(t);
  }
}

// mask -> mask * log2e (f32), 4096 elems
__global__ __launch_bounds__(256) void mask_prep(
    const float* __restrict__ m, float* __restrict__ o, int n) {
  int i = blockIdx.x * blockDim.x + threadIdx.x;
  if (i < n) o[i] = m[i] * LOG2E;
}

// ---------------- fused QKV projection: C = A @ W^T + b, head-major scatter ----
// Q output additionally scaled by 0.125*log2e (folded softmax scale).
__global__ __launch_bounds__(256, 2) void gemm_qkv(
    const bf16* __restrict__ A,
    const bf16* __restrict__ Wqp, const bf16* __restrict__ Wkp, const bf16* __restrict__ Wvp,
    const float* __restrict__ bqp, const float* __restrict__ bkp, const float* __restrict__ bvp,
    bf16* __restrict__ Cq, bf16* __restrict__ Ck, bf16* __restrict__ Cv) {
  const int bn_all = blockIdx.y;
  const bf16* W; const float* bias; bf16* C; int Hn; int bn;
  if (bn_all < 16)      { W = Wqp; bias = bqp; C = Cq; Hn = H_;  bn = bn_all; }
  else if (bn_all < 20) { W = Wkp; bias = bkp; C = Ck; Hn = KV_; bn = bn_all - 16; }
  else                  { W = Wvp; bias = bvp; C = Cv; Hn = KV_; bn = bn_all - 20; }
  const float oscale = (bn_all < 16) ? (0.125f * LOG2E) : 1.0f;

  __shared__ __align__(16) bf16 As[128 * 64];
  __shared__ __align__(16) bf16 Bs[128 * 64];
  const int tid = threadIdx.x;
  const int lane = tid & 63, wid = tid >> 6;
  const int wr = wid >> 1, wc = wid & 1;
  const int bm = blockIdx.x;
  const int K = HID_;

  f32x4 acc[4][4] = {};

  for (int k0 = 0; k0 < K; k0 += 64) {
    __syncthreads();
#pragma unroll
    for (int c = 0; c < 4; ++c) {
      const int r = c * 32 + wid * 8 + (lane >> 3);
      const int gcolb = ((lane & 7) * 16) ^ ((r & 7) << 4);
      gload_lds16(A + (size_t)(bm * 128 + r) * K + k0 + (gcolb >> 1),
                  &As[(c * 32 + wid * 8) * 64]);
      gload_lds16(W + (size_t)(bn * 128 + r) * K + k0 + (gcolb >> 1),
                  &Bs[(c * 32 + wid * 8) * 64]);
    }
    __syncthreads();
#pragma unroll
    for (int ks = 0; ks < 2; ++ks) {
      bf16x8 af[4], bfr[4];
#pragma unroll
      for (int i = 0; i < 4; ++i) {
        const int ra = wr * 64 + i * 16 + (lane & 15);
        const int ka = (ks * 64 + ((lane >> 4) << 4)) ^ ((ra & 7) << 4);
        af[i] = *(const bf16x8*)((const char*)As + ra * 128 + ka);
        const int rb = wc * 64 + i * 16 + (lane & 15);
        const int kb = (ks * 64 + ((lane >> 4) << 4)) ^ ((rb & 7) << 4);
        bfr[i] = *(const bf16x8*)((const char*)Bs + rb * 128 + kb);
      }
      __builtin_amdgcn_s_setprio(1);
#pragma unroll
      for (int i = 0; i < 4; ++i)
#pragma unroll
        for (int j = 0; j < 4; ++j)
          acc[i][j] = __builtin_amdgcn_mfma_f32_16x16x32_bf16(af[i], bfr[j], acc[i][j], 0, 0, 0);
      __builtin_amdgcn_s_setprio(0);
    }
  }

#pragma unroll
  for (int j = 0; j < 4; ++j) {
    const int n = bn * 128 + wc * 64 + j * 16 + (lane & 15);
    const float bv = bias[n];
#pragma unroll
    for (int i = 0; i < 4; ++i) {
      const int mb = bm * 128 + wr * 64 + i * 16 + ((lane >> 4) << 2);
#pragma unroll
      for (int e = 0; e < 4; ++e) {
        const int m = mb + e;
        const float v = (acc[i][j][e] + bv) * oscale;
        const int b = m >> 11, s = m & (S_ - 1);
        const int h = n >> 6, d = n & 63;
        C[(((size_t)b * Hn + h) * S_ + s) * 64 + d] = __float2bfloat16(v);
      }
    }
  }
}

// ---------------- output projection: out = A @ Wo^T + bo (f32 out) -------------
__global__ __launch_bounds__(256, 2) void gemm_out(
    const bf16* __restrict__ A, const bf16* __restrict__ W,
    const float* __restrict__ bias, float* __restrict__ C) {
  __shared__ __align__(16) bf16 As[128 * 64];
  __shared__ __align__(16) bf16 Bs[128 * 64];
  const int tid = threadIdx.x;
  const int lane = tid & 63, wid = tid >> 6;
  const int wr = wid >> 1, wc = wid & 1;
  const int bm = blockIdx.x, bn = blockIdx.y;
  const int K = HID_, N = HID_;

  f32x4 acc[4][4] = {};

  for (int k0 = 0; k0 < K; k0 += 64) {
    __syncthreads();
#pragma unroll
    for (int c = 0; c < 4; ++c) {
      const int r = c * 32 + wid * 8 + (lane >> 3);
      const int gcolb = ((lane & 7) * 16) ^ ((r & 7) << 4);
      gload_lds16(A + (size_t)(bm * 128 + r) * K + k0 + (gcolb >> 1),
                  &As[(c * 32 + wid * 8) * 64]);
      gload_lds16(W + (size_t)(bn * 128 + r) * K + k0 + (gcolb >> 1),
                  &Bs[(c * 32 + wid * 8) * 64]);
    }
    __syncthreads();
#pragma unroll
    for (int ks = 0; ks < 2; ++ks) {
      bf16x8 af[4], bfr[4];
#pragma unroll
      for (int i = 0; i < 4; ++i) {
        const int ra = wr * 64 + i * 16 + (lane & 15);
        const int ka = (ks * 64 + ((lane >> 4) << 4)) ^ ((ra & 7) << 4);
        af[i] = *(const bf16x8*)((const char*)As + ra * 128 + ka);
        const int rb = wc * 64 + i * 16 + (lane & 15);
        const int kb = (ks * 64 + ((lane >> 4) << 4)) ^ ((rb & 7) << 4);
        bfr[i] = *(const bf16x8*)((const char*)Bs + rb * 128 + kb);
      }
      __builtin_amdgcn_s_setprio(1);
#pragma unroll
      for (int i = 0; i < 4; ++i)
#pragma unroll
        for (int j = 0; j < 4; ++j)
          acc[i][j] = __builtin_amdgcn_mfma_f32_16x16x32_bf16(af[i], bfr[j], acc[i][j], 0, 0, 0);
      __builtin_amdgcn_s_setprio(0);
    }
  }

#pragma unroll
  for (int j = 0; j < 4; ++j) {
    const int n = bn * 128 + wc * 64 + j * 16 + (lane & 15);
    const float bv = bias[n];
#pragma unroll
    for (int i = 0; i < 4; ++i) {
      const int mb = bm * 128 + wr * 64 + i * 16 + ((lane >> 4) << 2);
#pragma unroll
      for (int e = 0; e < 4; ++e) {
        C[(size_t)(mb + e) * N + n] = acc[i][j][e] + bv;
      }
    }
  }
}

// ---------------- flash attention: 4 warps x 32 q-rows, swapped QK^T, 32x32 MFMA
// Q pre-scaled by 0.125*log2e; maskL = mask*log2e. Unnormalized softmax:
// s = QK (log2 units, mask folded into MFMA C-init); p = exp2(s); no max tracking.
__global__ __launch_bounds__(256, 4) void attn_fwd(
    const bf16* __restrict__ qb, const bf16* __restrict__ kb,
    const bf16* __restrict__ vb, const float* __restrict__ maskL,
    bf16* __restrict__ ob) {
  const int qtile = blockIdx.x;   // 0..15 (128 q-rows each)
  const int headid = blockIdx.y;  // 0..63
  const int b = headid >> 5, h = headid & (H_ - 1);
  const int kv = h >> 2;
  const int tid = threadIdx.x, lane = tid & 63, wid = tid >> 6;
  const int l31 = lane & 31, hi = lane >> 5;

  __shared__ __align__(16) bf16 Ks[2][64 * 64];
  __shared__ __align__(16) bf16 VTs[2][64 * 64];  // VT[d][key], swizzled
  __shared__ float lsm[4][32];

  const bf16* qh = qb + ((size_t)(b * H_ + h) * S_) * D_;
  const bf16* kh = kb + ((size_t)(b * KV_ + kv) * S_) * D_;
  const bf16* vh = vb + ((size_t)(b * KV_ + kv) * S_) * D_;
  const float* mrow = maskL + (size_t)b * S_;

  // Q B-frags: lane holds q=l31, d = ks*16 + hi*8 + j
  const int qrow = qtile * 128 + wid * 32 + l31;
  bf16x8 qf[4];
#pragma unroll
  for (int ks = 0; ks < 4; ++ks)
    qf[ks] = *(const bf16x8*)(qh + (size_t)qrow * D_ + ks * 16 + hi * 8);

  float lp = 0.f;
  f32x16 o[2] = {};

  // ---- prologue: stage tile 0
#pragma unroll
  for (int c = 0; c < 2; ++c) {
    const int r = c * 32 + wid * 8 + (lane >> 3);
    const int gcolb = ((lane & 7) * 16) ^ ((r & 7) << 4);
    gload_lds16(kh + (size_t)r * D_ + (gcolb >> 1), &Ks[0][(c * 32 + wid * 8) * 64]);
  }
  bf16x8 vn0 = *(const bf16x8*)(vh + (size_t)lane * D_ + wid * 16);
  bf16x8 vn1 = *(const bf16x8*)(vh + (size_t)lane * D_ + wid * 16 + 8);
  {
    const int key2 = lane * 2;
#pragma unroll
    for (int j2 = 0; j2 < 8; ++j2) {
      const int d0 = wid * 16 + j2;
      *(short*)((char*)&VTs[0][0] + d0 * 128 + (key2 ^ ((d0 & 7) << 4))) = vn0[j2];
      const int d1 = d0 + 8;
      *(short*)((char*)&VTs[0][0] + d1 * 128 + (key2 ^ ((d1 & 7) << 4))) = vn1[j2];
    }
  }
  __syncthreads();

  for (int t = 0; t < NT_; ++t) {
    const int cur = t & 1, nxt = cur ^ 1;

    // ---- prefetch tile t+1
    if (t < NT_ - 1) {
#pragma unroll
      for (int c = 0; c < 2; ++c) {
        const int r = c * 32 + wid * 8 + (lane >> 3);
        const int gcolb = ((lane & 7) * 16) ^ ((r & 7) << 4);
        gload_lds16(kh + ((size_t)(t + 1) * 64 + r) * D_ + (gcolb >> 1),
                    &Ks[nxt][(c * 32 + wid * 8) * 64]);
      }
      vn0 = *(const bf16x8*)(vh + ((size_t)(t + 1) * 64 + lane) * D_ + wid * 16);
      vn1 = *(const bf16x8*)(vh + ((size_t)(t + 1) * 64 + lane) * D_ + wid * 16 + 8);
    }

    // ---- QK^T (swapped), C-init = maskL in C/D layout (key = e + 8*rq + 4*hi)
    f32x16 s[2];
#pragma unroll
    for (int kbv = 0; kbv < 2; ++kbv) {
#pragma unroll
      for (int rq = 0; rq < 4; ++rq) {
        const f32x4 m4 = *(const f32x4*)(mrow + t * 64 + kbv * 32 + rq * 8 + 4 * hi);
#pragma unroll
        for (int e = 0; e < 4; ++e) s[kbv][rq * 4 + e] = m4[e];
      }
    }
#pragma unroll
    for (int kbv = 0; kbv < 2; ++kbv) {
      __builtin_amdgcn_s_setprio(1);
#pragma unroll
      for (int ks = 0; ks < 4; ++ks) {
        const int rk = kbv * 32 + l31;
        const int kbyte = (ks * 32 + hi * 16) ^ ((rk & 7) << 4);
        bf16x8 kf = *(const bf16x8*)((const char*)&Ks[cur][0] + rk * 128 + kbyte);
        s[kbv] = __builtin_amdgcn_mfma_f32_32x32x16_bf16(kf, qf[ks], s[kbv], 0, 0, 0);
      }
      __builtin_amdgcn_s_setprio(0);
    }

    // ---- unnormalized softmax: p = exp2(s); lane-local partial row sum
    float2 ps2 = make_float2(0.f, 0.f);
#pragma unroll
    for (int kbv = 0; kbv < 2; ++kbv)
#pragma unroll
      for (int r8 = 0; r8 < 8; ++r8) {
        const float pa_ = fexp2(s[kbv][2 * r8]);
        const float pb_ = fexp2(s[kbv][2 * r8 + 1]);
        s[kbv][2 * r8] = pa_;
        s[kbv][2 * r8 + 1] = pb_;
        ps2.x += pa_;
        ps2.y += pb_;
      }
    lp += ps2.x + ps2.y;

    // ---- build P A-frags (cvt_pk + permlane32_swap)
    bf16x8 pa[2][2];
#pragma unroll
    for (int kbv = 0; kbv < 2; ++kbv) {
      uint32_t a0 = cvtpk_bf16(s[kbv][0], s[kbv][1]);
      uint32_t b0 = cvtpk_bf16(s[kbv][4], s[kbv][5]);
      plane32_swap(a0, b0);
      uint32_t a1 = cvtpk_bf16(s[kbv][2], s[kbv][3]);
      uint32_t b1 = cvtpk_bf16(s[kbv][6], s[kbv][7]);
      plane32_swap(a1, b1);
      i32x4 t0; t0[0] = (int)a0; t0[1] = (int)a1; t0[2] = (int)b0; t0[3] = (int)b1;
      pa[kbv][0] = __builtin_bit_cast(bf16x8, t0);
      uint32_t a2 = cvtpk_bf16(s[kbv][8], s[kbv][9]);
      uint32_t b2 = cvtpk_bf16(s[kbv][12], s[kbv][13]);
      plane32_swap(a2, b2);
      uint32_t a3 = cvtpk_bf16(s[kbv][10], s[kbv][11]);
      uint32_t b3 = cvtpk_bf16(s[kbv][14], s[kbv][15]);
      plane32_swap(a3, b3);
      i32x4 t1; t1[0] = (int)a2; t1[1] = (int)a3; t1[2] = (int)b2; t1[3] = (int)b3;
      pa[kbv][1] = __builtin_bit_cast(bf16x8, t1);
    }

    // ---- PV: o[db] += P @ V
#pragma unroll
    for (int db = 0; db < 2; ++db) {
      __builtin_amdgcn_s_setprio(1);
#pragma unroll
      for (int kbv = 0; kbv < 2; ++kbv)
#pragma unroll
        for (int ks2 = 0; ks2 < 2; ++ks2) {
          const int rd = db * 32 + l31;
          const int vbyte = (kbv * 64 + ks2 * 32 + hi * 16) ^ ((rd & 7) << 4);
          bf16x8 vf = *(const bf16x8*)((const char*)&VTs[cur][0] + rd * 128 + vbyte);
          o[db] = __builtin_amdgcn_mfma_f32_32x32x16_bf16(pa[kbv][ks2], vf, o[db], 0, 0, 0);
        }
      __builtin_amdgcn_s_setprio(0);
    }

    __syncthreads();
    if (t < NT_ - 1) {
      const int key2 = lane * 2;
#pragma unroll
      for (int j2 = 0; j2 < 8; ++j2) {
        const int d0 = wid * 16 + j2;
        *(short*)((char*)&VTs[nxt][0] + d0 * 128 + (key2 ^ ((d0 & 7) << 4))) = vn0[j2];
        const int d1 = d0 + 8;
        *(short*)((char*)&VTs[nxt][0] + d1 * 128 + (key2 ^ ((d1 & 7) << 4))) = vn1[j2];
      }
    }
    __syncthreads();
  }

  // ---- epilogue: row sum l (pair add), redistribute to C/D layout, write
  {
    uint32_t la = __float_as_uint(lp), lb = la;
    plane32_swap(la, lb);
    const float lsum = __uint_as_float(la) + __uint_as_float(lb);
    lsm[wid][l31] = lsum;
  }
  __syncthreads();
#pragma unroll
  for (int rq = 0; rq < 4; ++rq) {
    const f32x4 l4 = *(const f32x4*)&lsm[wid][rq * 8 + 4 * hi];
#pragma unroll
    for (int e2 = 0; e2 < 4; ++e2) {
      const float inv = 1.0f / l4[e2];
      const int q_out = e2 + 8 * rq + 4 * hi;
      const int srow = qtile * 128 + wid * 32 + q_out;
#pragma unroll
      for (int db = 0; db < 2; ++db) {
        const float val = o[db][rq * 4 + e2] * inv;
        ob[((size_t)b * S_ + srow) * HID_ + h * 64 + db * 32 + l31] = __float2bfloat16(val);
      }
    }
  }
}

extern "C" void kernel_launch(void* const* d_in, const int* in_sizes, int n_in,
                              void* d_out, int out_size, void* d_ws, size_t ws_size,
                              hipStream_t stream) {
  (void)in_sizes; (void)n_in; (void)out_size; (void)ws_size;
  const float* x  = (const float*)d_in[0];
  const float* am = (const float*)d_in[1];
  const float* Wq = (const float*)d_in[2];
  const float* bq = (const float*)d_in[3];
  const float* Wk = (const float*)d_in[4];
  const float* bk = (const float*)d_in[5];
  const float* Wv = (const float*)d_in[6];
  const float* bv = (const float*)d_in[7];
  const float* Wo = (const float*)d_in[8];
  const float* bo = (const float*)d_in[9];
  float* out = (float*)d_out;

  const size_t XE  = (size_t)B_ * S_ * HID_;
  const size_t WQE = (size_t)HID_ * HID_;
  const size_t WKE = (size_t)(KV_ * D_) * HID_;
  const size_t QE  = (size_t)B_ * H_ * S_ * D_;
  const size_t KE  = (size_t)B_ * KV_ * S_ * D_;

  bf16* xb  = (bf16*)d_ws;
  bf16* wqb = xb + XE;
  bf16* wkb = wqb + WQE;
  bf16* wvb = wkb + WKE;
  bf16* wob = wvb + WKE;
  bf16* qbuf = wob + WQE;
  bf16* kbuf = qbuf + QE;
  bf16* vbuf = kbuf + KE;
  bf16* abuf = vbuf + KE;
  float* maskL = (float*)(abuf + XE);  // [B,S] f32

  dim3 blk(256);
  cvt_f32_bf16<<<2048, blk, 0, stream>>>(x,  xb,  (int)(XE / 4));
  cvt_f32_bf16<<<2048, blk, 0, stream>>>(Wq, wqb, (int)(WQE / 4));
  cvt_f32_bf16<<<1024, blk, 0, stream>>>(Wk, wkb, (int)(WKE / 4));
  cvt_f32_bf16<<<1024, blk, 0, stream>>>(Wv, wvb, (int)(WKE / 4));
  cvt_f32_bf16<<<2048, blk, 0, stream>>>(Wo, wob, (int)(WQE / 4));
  mask_prep<<<(B_ * S_ + 255) / 256, blk, 0, stream>>>(am, maskL, B_ * S_);

  const int M = B_ * S_;
  gemm_qkv<<<dim3(M / 128, 24), blk, 0, stream>>>(xb, wqb, wkb, wvb, bq, bk, bv,
                                                  qbuf, kbuf, vbuf);
  attn_fwd<<<dim3(S_ / 128, B_ * H_), blk, 0, stream>>>(qbuf, kbuf, vbuf, maskL, abuf);
  gemm_out<<<dim3(M / 128, HID_ / 128), blk, 0, stream>>>(abuf, wob, bo, out);
}

// Round 6
// 202.451 us; speedup vs baseline: 1.9542x; 1.0351x over previous
//
#include <hip/hip_runtime.h>
#include <hip/hip_bf16.h>
#include <stdint.h>

typedef __hip_bfloat16 bf16;
typedef __attribute__((ext_vector_type(8))) short bf16x8;
typedef __attribute__((ext_vector_type(4))) float f32x4;
typedef __attribute__((ext_vector_type(16))) float f32x16;
typedef __attribute__((ext_vector_type(4))) int i32x4;
typedef __attribute__((ext_vector_type(2))) int i32x2;

#define B_   2
#define S_   2048
#define HID_ 2048
#define H_   32
#define KV_  8
#define D_   64
#define NT_  (S_ / 64)
#define LOG2E 1.4426950408889634f

__device__ __forceinline__ void gload_lds16(const void* g, void* l) {
  __builtin_amdgcn_global_load_lds(
      (const __attribute__((address_space(1))) uint32_t*)g,
      (__attribute__((address_space(3))) uint32_t*)l, 16, 0, 0);
}
__device__ __forceinline__ float fexp2(float x) { return __builtin_amdgcn_exp2f(x); }

__device__ __forceinline__ uint32_t cvtpk_bf16(float lo, float hi) {
  uint32_t r;
  asm("v_cvt_pk_bf16_f32 %0, %1, %2" : "=v"(r) : "v"(lo), "v"(hi));
  return r;
}
__device__ __forceinline__ void plane32_swap(uint32_t& a, uint32_t& b) {
  i32x2 r = __builtin_amdgcn_permlane32_swap((int)a, (int)b, false, false);
  a = (uint32_t)r[0]; b = (uint32_t)r[1];
}

// f32 -> bf16 elementwise (RN), vectorized 4/thread, grid-stride.
__global__ __launch_bounds__(256) void cvt_f32_bf16(
    const float* __restrict__ s, bf16* __restrict__ d, int n4) {
  int i = blockIdx.x * blockDim.x + threadIdx.x;
  const int stride = gridDim.x * blockDim.x;
  for (; i < n4; i += stride) {
    float4 v = ((const float4*)s)[i];
    bf16 t[4];
    t[0] = __float2bfloat16(v.x);
    t[1] = __float2bfloat16(v.y);
    t[2] = __float2bfloat16(v.z);
    t[3] = __float2bfloat16(v.w);
    *reinterpret_cast<uint64_t*>(d + 4 * (size_t)i) = *reinterpret_cast<uint64_t*>(t);
  }
}

// mask -> mask * log2e (f32)
__global__ __launch_bounds__(256) void mask_prep(
    const float* __restrict__ m, float* __restrict__ o, int n) {
  int i = blockIdx.x * blockDim.x + threadIdx.x;
  if (i < n) o[i] = m[i] * LOG2E;
}

// ---------------- fused QKV projection ----------------
// Q (scaled by 0.125*log2e) and K -> head-major [B,Hn,S,D].
// V -> transposed [B,KV,D,S]  (so attention can DMA-stage V^T directly).
__global__ __launch_bounds__(256, 2) void gemm_qkv(
    const bf16* __restrict__ A,
    const bf16* __restrict__ Wqp, const bf16* __restrict__ Wkp, const bf16* __restrict__ Wvp,
    const float* __restrict__ bqp, const float* __restrict__ bkp, const float* __restrict__ bvp,
    bf16* __restrict__ Cq, bf16* __restrict__ Ck, bf16* __restrict__ Cv) {
  // bijective XCD swizzle (768 blocks, 768%8==0)
  const int lid0 = blockIdx.y * gridDim.x + blockIdx.x;
  const int q8 = (int)(gridDim.x * gridDim.y) >> 3;
  const int lid = (lid0 & 7) * q8 + (lid0 >> 3);
  const int bm = lid & 31;        // gridDim.x == 32
  const int bn_all = lid >> 5;

  const bf16* W; const float* bias; int bn;
  if (bn_all < 16)      { W = Wqp; bias = bqp; bn = bn_all; }
  else if (bn_all < 20) { W = Wkp; bias = bkp; bn = bn_all - 16; }
  else                  { W = Wvp; bias = bvp; bn = bn_all - 20; }
  const float oscale = (bn_all < 16) ? (0.125f * LOG2E) : 1.0f;

  __shared__ __align__(16) bf16 As[128 * 64];
  __shared__ __align__(16) bf16 Bs[128 * 64];
  const int tid = threadIdx.x;
  const int lane = tid & 63, wid = tid >> 6;
  const int wr = wid >> 1, wc = wid & 1;
  const int K = HID_;

  f32x4 acc[4][4] = {};

  for (int k0 = 0; k0 < K; k0 += 64) {
    __syncthreads();
#pragma unroll
    for (int c = 0; c < 4; ++c) {
      const int r = c * 32 + wid * 8 + (lane >> 3);
      const int gcolb = ((lane & 7) * 16) ^ ((r & 7) << 4);
      gload_lds16(A + (size_t)(bm * 128 + r) * K + k0 + (gcolb >> 1),
                  &As[(c * 32 + wid * 8) * 64]);
      gload_lds16(W + (size_t)(bn * 128 + r) * K + k0 + (gcolb >> 1),
                  &Bs[(c * 32 + wid * 8) * 64]);
    }
    __syncthreads();
#pragma unroll
    for (int ks = 0; ks < 2; ++ks) {
      bf16x8 af[4], bfr[4];
#pragma unroll
      for (int i = 0; i < 4; ++i) {
        const int ra = wr * 64 + i * 16 + (lane & 15);
        const int ka = (ks * 64 + ((lane >> 4) << 4)) ^ ((ra & 7) << 4);
        af[i] = *(const bf16x8*)((const char*)As + ra * 128 + ka);
        const int rb = wc * 64 + i * 16 + (lane & 15);
        const int kb = (ks * 64 + ((lane >> 4) << 4)) ^ ((rb & 7) << 4);
        bfr[i] = *(const bf16x8*)((const char*)Bs + rb * 128 + kb);
      }
      __builtin_amdgcn_s_setprio(1);
#pragma unroll
      for (int i = 0; i < 4; ++i)
#pragma unroll
        for (int j = 0; j < 4; ++j)
          acc[i][j] = __builtin_amdgcn_mfma_f32_16x16x32_bf16(af[i], bfr[j], acc[i][j], 0, 0, 0);
      __builtin_amdgcn_s_setprio(0);
    }
  }

  if (bn_all < 20) {
    // Q/K: head-major scatter [B,Hn,S,D]
    const int Hn = (bn_all < 16) ? H_ : KV_;
    bf16* C = (bn_all < 16) ? Cq : Ck;
#pragma unroll
    for (int j = 0; j < 4; ++j) {
      const int n = bn * 128 + wc * 64 + j * 16 + (lane & 15);
      const float bv = bias[n];
#pragma unroll
      for (int i = 0; i < 4; ++i) {
        const int mb = bm * 128 + wr * 64 + i * 16 + ((lane >> 4) << 2);
#pragma unroll
        for (int e = 0; e < 4; ++e) {
          const int m = mb + e;
          const float v = (acc[i][j][e] + bv) * oscale;
          const int b = m >> 11, s = m & (S_ - 1);
          const int h = n >> 6, d = n & 63;
          C[(((size_t)b * Hn + h) * S_ + s) * 64 + d] = __float2bfloat16(v);
        }
      }
    }
  } else {
    // V^T: [B,KV,D,S], lane holds 4 consecutive s -> packed 8B stores
#pragma unroll
    for (int j = 0; j < 4; ++j) {
      const int n = bn * 128 + wc * 64 + j * 16 + (lane & 15);
      const int kvh = n >> 6, d = n & 63;
      const float bv = bias[n];
#pragma unroll
      for (int i = 0; i < 4; ++i) {
        const int m0 = bm * 128 + wr * 64 + i * 16 + ((lane >> 4) << 2);
        const int b = m0 >> 11, s0 = m0 & (S_ - 1);
        bf16 t4[4];
#pragma unroll
        for (int e = 0; e < 4; ++e) t4[e] = __float2bfloat16(acc[i][j][e] + bv);
        *reinterpret_cast<uint64_t*>(
            Cv + (((size_t)b * KV_ + kvh) * D_ + d) * S_ + s0) =
            *reinterpret_cast<uint64_t*>(t4);
      }
    }
  }
}

// ---------------- output projection: out = A @ Wo^T + bo (f32 out) -------------
__global__ __launch_bounds__(256, 2) void gemm_out(
    const bf16* __restrict__ A, const bf16* __restrict__ W,
    const float* __restrict__ bias, float* __restrict__ C) {
  const int lid0 = blockIdx.y * gridDim.x + blockIdx.x;
  const int q8 = (int)(gridDim.x * gridDim.y) >> 3;
  const int lid = (lid0 & 7) * q8 + (lid0 >> 3);
  const int bm = lid & 31;   // gridDim.x == 32
  const int bn = lid >> 5;

  __shared__ __align__(16) bf16 As[128 * 64];
  __shared__ __align__(16) bf16 Bs[128 * 64];
  const int tid = threadIdx.x;
  const int lane = tid & 63, wid = tid >> 6;
  const int wr = wid >> 1, wc = wid & 1;
  const int K = HID_, N = HID_;

  f32x4 acc[4][4] = {};

  for (int k0 = 0; k0 < K; k0 += 64) {
    __syncthreads();
#pragma unroll
    for (int c = 0; c < 4; ++c) {
      const int r = c * 32 + wid * 8 + (lane >> 3);
      const int gcolb = ((lane & 7) * 16) ^ ((r & 7) << 4);
      gload_lds16(A + (size_t)(bm * 128 + r) * K + k0 + (gcolb >> 1),
                  &As[(c * 32 + wid * 8) * 64]);
      gload_lds16(W + (size_t)(bn * 128 + r) * K + k0 + (gcolb >> 1),
                  &Bs[(c * 32 + wid * 8) * 64]);
    }
    __syncthreads();
#pragma unroll
    for (int ks = 0; ks < 2; ++ks) {
      bf16x8 af[4], bfr[4];
#pragma unroll
      for (int i = 0; i < 4; ++i) {
        const int ra = wr * 64 + i * 16 + (lane & 15);
        const int ka = (ks * 64 + ((lane >> 4) << 4)) ^ ((ra & 7) << 4);
        af[i] = *(const bf16x8*)((const char*)As + ra * 128 + ka);
        const int rb = wc * 64 + i * 16 + (lane & 15);
        const int kb = (ks * 64 + ((lane >> 4) << 4)) ^ ((rb & 7) << 4);
        bfr[i] = *(const bf16x8*)((const char*)Bs + rb * 128 + kb);
      }
      __builtin_amdgcn_s_setprio(1);
#pragma unroll
      for (int i = 0; i < 4; ++i)
#pragma unroll
        for (int j = 0; j < 4; ++j)
          acc[i][j] = __builtin_amdgcn_mfma_f32_16x16x32_bf16(af[i], bfr[j], acc[i][j], 0, 0, 0);
      __builtin_amdgcn_s_setprio(0);
    }
  }

#pragma unroll
  for (int j = 0; j < 4; ++j) {
    const int n = bn * 128 + wc * 64 + j * 16 + (lane & 15);
    const float bv = bias[n];
#pragma unroll
    for (int i = 0; i < 4; ++i) {
      const int mb = bm * 128 + wr * 64 + i * 16 + ((lane >> 4) << 2);
#pragma unroll
      for (int e = 0; e < 4; ++e) {
        C[(size_t)(mb + e) * N + n] = acc[i][j][e] + bv;
      }
    }
  }
}

// ---------------- flash attention: 4 warps x 32 q-rows, swapped QK^T, 32x32 MFMA
// Q pre-scaled by 0.125*log2e; maskL = mask*log2e; V supplied TRANSPOSED
// [B,KV,D,S] so both K and V^T stage via global_load_lds (linear dest,
// pre-swizzled source). Unnormalized softmax: p = exp2(s), no max tracking.
__global__ __launch_bounds__(256, 4) void attn_fwd(
    const bf16* __restrict__ qb, const bf16* __restrict__ kb,
    const bf16* __restrict__ vtb, const float* __restrict__ maskL,
    bf16* __restrict__ ob) {
  // bijective XCD swizzle (1024 blocks)
  const int lid0 = blockIdx.y * gridDim.x + blockIdx.x;
  const int q8 = (int)(gridDim.x * gridDim.y) >> 3;
  const int lid = (lid0 & 7) * q8 + (lid0 >> 3);
  const int qtile = lid & 15;     // gridDim.x == 16
  const int headid = lid >> 4;
  const int b = headid >> 5, h = headid & (H_ - 1);
  const int kv = h >> 2;
  const int tid = threadIdx.x, lane = tid & 63, wid = tid >> 6;
  const int l31 = lane & 31, hi = lane >> 5;

  __shared__ __align__(16) bf16 Ks[2][64 * 64];
  __shared__ __align__(16) bf16 VTs[2][64 * 64];  // VT[d][key], source-swizzled
  __shared__ float lsm[4][32];

  const bf16* qh = qb + ((size_t)(b * H_ + h) * S_) * D_;
  const bf16* kh = kb + ((size_t)(b * KV_ + kv) * S_) * D_;
  const bf16* vth = vtb + (size_t)(b * KV_ + kv) * D_ * S_;
  const float* mrow = maskL + (size_t)b * S_;

  // Q B-frags: lane holds q=l31, d = ks*16 + hi*8 + j
  const int qrow = qtile * 128 + wid * 32 + l31;
  bf16x8 qf[4];
#pragma unroll
  for (int ks = 0; ks < 4; ++ks)
    qf[ks] = *(const bf16x8*)(qh + (size_t)qrow * D_ + ks * 16 + hi * 8);

  float lp = 0.f;
  f32x16 o[2] = {};

  // ---- stage tile 0 (K rows = keys; VT rows = d, cols = keys at t*64)
#pragma unroll
  for (int c = 0; c < 2; ++c) {
    const int r = c * 32 + wid * 8 + (lane >> 3);
    const int gcolb = ((lane & 7) * 16) ^ ((r & 7) << 4);
    gload_lds16(kh + (size_t)r * D_ + (gcolb >> 1), &Ks[0][(c * 32 + wid * 8) * 64]);
    gload_lds16(vth + (size_t)r * S_ + (gcolb >> 1), &VTs[0][(c * 32 + wid * 8) * 64]);
  }
  __syncthreads();

  for (int t = 0; t < NT_; ++t) {
    const int cur = t & 1, nxt = cur ^ 1;

    // ---- prefetch tile t+1 into [nxt]
    if (t < NT_ - 1) {
#pragma unroll
      for (int c = 0; c < 2; ++c) {
        const int r = c * 32 + wid * 8 + (lane >> 3);
        const int gcolb = ((lane & 7) * 16) ^ ((r & 7) << 4);
        gload_lds16(kh + ((size_t)(t + 1) * 64 + r) * D_ + (gcolb >> 1),
                    &Ks[nxt][(c * 32 + wid * 8) * 64]);
        gload_lds16(vth + (size_t)r * S_ + (t + 1) * 64 + (gcolb >> 1),
                    &VTs[nxt][(c * 32 + wid * 8) * 64]);
      }
    }

    // ---- QK^T (swapped), C-init = maskL in C/D layout (key = e + 8*rq + 4*hi)
    f32x16 s[2];
#pragma unroll
    for (int kbv = 0; kbv < 2; ++kbv) {
#pragma unroll
      for (int rq = 0; rq < 4; ++rq) {
        const f32x4 m4 = *(const f32x4*)(mrow + t * 64 + kbv * 32 + rq * 8 + 4 * hi);
#pragma unroll
        for (int e = 0; e < 4; ++e) s[kbv][rq * 4 + e] = m4[e];
      }
    }
#pragma unroll
    for (int kbv = 0; kbv < 2; ++kbv) {
      __builtin_amdgcn_s_setprio(1);
#pragma unroll
      for (int ks = 0; ks < 4; ++ks) {
        const int rk = kbv * 32 + l31;
        const int kbyte = (ks * 32 + hi * 16) ^ ((rk & 7) << 4);
        bf16x8 kf = *(const bf16x8*)((const char*)&Ks[cur][0] + rk * 128 + kbyte);
        s[kbv] = __builtin_amdgcn_mfma_f32_32x32x16_bf16(kf, qf[ks], s[kbv], 0, 0, 0);
      }
      __builtin_amdgcn_s_setprio(0);
    }

    // ---- unnormalized softmax: p = exp2(s); lane-local partial row sum
    float2 ps2 = make_float2(0.f, 0.f);
#pragma unroll
    for (int kbv = 0; kbv < 2; ++kbv)
#pragma unroll
      for (int r8 = 0; r8 < 8; ++r8) {
        const float pa_ = fexp2(s[kbv][2 * r8]);
        const float pb_ = fexp2(s[kbv][2 * r8 + 1]);
        s[kbv][2 * r8] = pa_;
        s[kbv][2 * r8 + 1] = pb_;
        ps2.x += pa_;
        ps2.y += pb_;
      }
    lp += ps2.x + ps2.y;

    // ---- build P A-frags (cvt_pk + permlane32_swap)
    bf16x8 pa[2][2];
#pragma unroll
    for (int kbv = 0; kbv < 2; ++kbv) {
      uint32_t a0 = cvtpk_bf16(s[kbv][0], s[kbv][1]);
      uint32_t b0 = cvtpk_bf16(s[kbv][4], s[kbv][5]);
      plane32_swap(a0, b0);
      uint32_t a1 = cvtpk_bf16(s[kbv][2], s[kbv][3]);
      uint32_t b1 = cvtpk_bf16(s[kbv][6], s[kbv][7]);
      plane32_swap(a1, b1);
      i32x4 t0; t0[0] = (int)a0; t0[1] = (int)a1; t0[2] = (int)b0; t0[3] = (int)b1;
      pa[kbv][0] = __builtin_bit_cast(bf16x8, t0);
      uint32_t a2 = cvtpk_bf16(s[kbv][8], s[kbv][9]);
      uint32_t b2 = cvtpk_bf16(s[kbv][12], s[kbv][13]);
      plane32_swap(a2, b2);
      uint32_t a3 = cvtpk_bf16(s[kbv][10], s[kbv][11]);
      uint32_t b3 = cvtpk_bf16(s[kbv][14], s[kbv][15]);
      plane32_swap(a3, b3);
      i32x4 t1; t1[0] = (int)a2; t1[1] = (int)a3; t1[2] = (int)b2; t1[3] = (int)b3;
      pa[kbv][1] = __builtin_bit_cast(bf16x8, t1);
    }

    // ---- PV: o[db] += P @ V
#pragma unroll
    for (int db = 0; db < 2; ++db) {
      __builtin_amdgcn_s_setprio(1);
#pragma unroll
      for (int kbv = 0; kbv < 2; ++kbv)
#pragma unroll
        for (int ks2 = 0; ks2 < 2; ++ks2) {
          const int rd = db * 32 + l31;
          const int vbyte = (kbv * 64 + ks2 * 32 + hi * 16) ^ ((rd & 7) << 4);
          bf16x8 vf = *(const bf16x8*)((const char*)&VTs[cur][0] + rd * 128 + vbyte);
          o[db] = __builtin_amdgcn_mfma_f32_32x32x16_bf16(pa[kbv][ks2], vf, o[db], 0, 0, 0);
        }
      __builtin_amdgcn_s_setprio(0);
    }

    // single barrier per tile: drains prefetch (vmcnt) + guards [cur] reuse
    __syncthreads();
  }

  // ---- epilogue: row sum l (pair add), redistribute to C/D layout, write
  {
    uint32_t la = __float_as_uint(lp), lb = la;
    plane32_swap(la, lb);
    const float lsum = __uint_as_float(la) + __uint_as_float(lb);
    lsm[wid][l31] = lsum;
  }
  __syncthreads();
#pragma unroll
  for (int rq = 0; rq < 4; ++rq) {
    const f32x4 l4 = *(const f32x4*)&lsm[wid][rq * 8 + 4 * hi];
#pragma unroll
    for (int e2 = 0; e2 < 4; ++e2) {
      const float inv = 1.0f / l4[e2];
      const int q_out = e2 + 8 * rq + 4 * hi;
      const int srow = qtile * 128 + wid * 32 + q_out;
#pragma unroll
      for (int db = 0; db < 2; ++db) {
        const float val = o[db][rq * 4 + e2] * inv;
        ob[((size_t)b * S_ + srow) * HID_ + h * 64 + db * 32 + l31] = __float2bfloat16(val);
      }
    }
  }
}

extern "C" void kernel_launch(void* const* d_in, const int* in_sizes, int n_in,
                              void* d_out, int out_size, void* d_ws, size_t ws_size,
                              hipStream_t stream) {
  (void)in_sizes; (void)n_in; (void)out_size; (void)ws_size;
  const float* x  = (const float*)d_in[0];
  const float* am = (const float*)d_in[1];
  const float* Wq = (const float*)d_in[2];
  const float* bq = (const float*)d_in[3];
  const float* Wk = (const float*)d_in[4];
  const float* bk = (const float*)d_in[5];
  const float* Wv = (const float*)d_in[6];
  const float* bv = (const float*)d_in[7];
  const float* Wo = (const float*)d_in[8];
  const float* bo = (const float*)d_in[9];
  float* out = (float*)d_out;

  const size_t XE  = (size_t)B_ * S_ * HID_;
  const size_t WQE = (size_t)HID_ * HID_;
  const size_t WKE = (size_t)(KV_ * D_) * HID_;
  const size_t QE  = (size_t)B_ * H_ * S_ * D_;
  const size_t KE  = (size_t)B_ * KV_ * S_ * D_;

  bf16* xb  = (bf16*)d_ws;
  bf16* wqb = xb + XE;
  bf16* wkb = wqb + WQE;
  bf16* wvb = wkb + WKE;
  bf16* wob = wvb + WKE;
  bf16* qbuf = wob + WQE;
  bf16* kbuf = qbuf + QE;
  bf16* vtbuf = kbuf + KE;   // V^T [B,KV,D,S]
  bf16* abuf = vtbuf + KE;
  float* maskL = (float*)(abuf + XE);  // [B,S] f32

  dim3 blk(256);
  cvt_f32_bf16<<<2048, blk, 0, stream>>>(x,  xb,  (int)(XE / 4));
  cvt_f32_bf16<<<2048, blk, 0, stream>>>(Wq, wqb, (int)(WQE / 4));
  cvt_f32_bf16<<<1024, blk, 0, stream>>>(Wk, wkb, (int)(WKE / 4));
  cvt_f32_bf16<<<1024, blk, 0, stream>>>(Wv, wvb, (int)(WKE / 4));
  cvt_f32_bf16<<<2048, blk, 0, stream>>>(Wo, wob, (int)(WQE / 4));
  mask_prep<<<(B_ * S_ + 255) / 256, blk, 0, stream>>>(am, maskL, B_ * S_);

  const int M = B_ * S_;
  gemm_qkv<<<dim3(M / 128, 24), blk, 0, stream>>>(xb, wqb, wkb, wvb, bq, bk, bv,
                                                  qbuf, kbuf, vtbuf);
  attn_fwd<<<dim3(S_ / 128, B_ * H_), blk, 0, stream>>>(qbuf, kbuf, vtbuf, maskL, abuf);
  gemm_out<<<dim3(M / 128, HID_ / 128), blk, 0, stream>>>(abuf, wob, bo, out);
}

// Round 7
// 192.210 us; speedup vs baseline: 2.0583x; 1.0533x over previous
//
#include <hip/hip_runtime.h>
#include <hip/hip_bf16.h>
#include <stdint.h>

typedef __hip_bfloat16 bf16;
typedef __attribute__((ext_vector_type(8))) short bf16x8;
typedef __attribute__((ext_vector_type(4))) float f32x4;
typedef __attribute__((ext_vector_type(16))) float f32x16;
typedef __attribute__((ext_vector_type(4))) int i32x4;
typedef __attribute__((ext_vector_type(2))) int i32x2;

#define B_   2
#define S_   2048
#define HID_ 2048
#define H_   32
#define KV_  8
#define D_   64
#define NT_  (S_ / 64)
#define LOG2E 1.4426950408889634f

__device__ __forceinline__ void gload_lds16(const void* g, void* l) {
  __builtin_amdgcn_global_load_lds(
      (const __attribute__((address_space(1))) uint32_t*)g,
      (__attribute__((address_space(3))) uint32_t*)l, 16, 0, 0);
}
__device__ __forceinline__ float fexp2(float x) { return __builtin_amdgcn_exp2f(x); }

__device__ __forceinline__ uint32_t cvtpk_bf16(float lo, float hi) {
  uint32_t r;
  asm("v_cvt_pk_bf16_f32 %0, %1, %2" : "=v"(r) : "v"(lo), "v"(hi));
  return r;
}
__device__ __forceinline__ void plane32_swap(uint32_t& a, uint32_t& b) {
  i32x2 r = __builtin_amdgcn_permlane32_swap((int)a, (int)b, false, false);
  a = (uint32_t)r[0]; b = (uint32_t)r[1];
}

// ---- fused f32 -> bf16 conversion over 5 buffers (one launch) ----
struct CvtJob { const float* s; bf16* d; int n4; };
__global__ __launch_bounds__(256) void cvt_multi(
    CvtJob j0, CvtJob j1, CvtJob j2, CvtJob j3, CvtJob j4) {
  CvtJob j;
  switch (blockIdx.y) {
    case 0: j = j0; break;
    case 1: j = j1; break;
    case 2: j = j2; break;
    case 3: j = j3; break;
    default: j = j4; break;
  }
  int i = blockIdx.x * blockDim.x + threadIdx.x;
  const int stride = gridDim.x * blockDim.x;
  for (; i < j.n4; i += stride) {
    float4 v = ((const float4*)j.s)[i];
    bf16 t[4];
    t[0] = __float2bfloat16(v.x);
    t[1] = __float2bfloat16(v.y);
    t[2] = __float2bfloat16(v.z);
    t[3] = __float2bfloat16(v.w);
    *reinterpret_cast<uint64_t*>(j.d + 4 * (size_t)i) = *reinterpret_cast<uint64_t*>(t);
  }
}

// mask -> mask * log2e (f32)
__global__ __launch_bounds__(256) void mask_prep(
    const float* __restrict__ m, float* __restrict__ o, int n) {
  int i = blockIdx.x * blockDim.x + threadIdx.x;
  if (i < n) o[i] = m[i] * LOG2E;
}

// ---------------- fused QKV projection ----------------
// Q (scaled by 0.125*log2e) and K -> head-major [B,Hn,S,D].
// V -> transposed [B,KV,D,S]  (so attention can DMA-stage V^T directly).
__global__ __launch_bounds__(256, 2) void gemm_qkv(
    const bf16* __restrict__ A,
    const bf16* __restrict__ Wqp, const bf16* __restrict__ Wkp, const bf16* __restrict__ Wvp,
    const float* __restrict__ bqp, const float* __restrict__ bkp, const float* __restrict__ bvp,
    bf16* __restrict__ Cq, bf16* __restrict__ Ck, bf16* __restrict__ Cv) {
  const int lid0 = blockIdx.y * gridDim.x + blockIdx.x;
  const int q8 = (int)(gridDim.x * gridDim.y) >> 3;
  const int lid = (lid0 & 7) * q8 + (lid0 >> 3);
  const int bm = lid & 31;        // gridDim.x == 32
  const int bn_all = lid >> 5;

  const bf16* W; const float* bias; int bn;
  if (bn_all < 16)      { W = Wqp; bias = bqp; bn = bn_all; }
  else if (bn_all < 20) { W = Wkp; bias = bkp; bn = bn_all - 16; }
  else                  { W = Wvp; bias = bvp; bn = bn_all - 20; }
  const float oscale = (bn_all < 16) ? (0.125f * LOG2E) : 1.0f;

  __shared__ __align__(16) bf16 As[128 * 64];
  __shared__ __align__(16) bf16 Bs[128 * 64];
  const int tid = threadIdx.x;
  const int lane = tid & 63, wid = tid >> 6;
  const int wr = wid >> 1, wc = wid & 1;
  const int K = HID_;

  f32x4 acc[4][4] = {};

  for (int k0 = 0; k0 < K; k0 += 64) {
    __syncthreads();
#pragma unroll
    for (int c = 0; c < 4; ++c) {
      const int r = c * 32 + wid * 8 + (lane >> 3);
      const int gcolb = ((lane & 7) * 16) ^ ((r & 7) << 4);
      gload_lds16(A + (size_t)(bm * 128 + r) * K + k0 + (gcolb >> 1),
                  &As[(c * 32 + wid * 8) * 64]);
      gload_lds16(W + (size_t)(bn * 128 + r) * K + k0 + (gcolb >> 1),
                  &Bs[(c * 32 + wid * 8) * 64]);
    }
    __syncthreads();
#pragma unroll
    for (int ks = 0; ks < 2; ++ks) {
      bf16x8 af[4], bfr[4];
#pragma unroll
      for (int i = 0; i < 4; ++i) {
        const int ra = wr * 64 + i * 16 + (lane & 15);
        const int ka = (ks * 64 + ((lane >> 4) << 4)) ^ ((ra & 7) << 4);
        af[i] = *(const bf16x8*)((const char*)As + ra * 128 + ka);
        const int rb = wc * 64 + i * 16 + (lane & 15);
        const int kb = (ks * 64 + ((lane >> 4) << 4)) ^ ((rb & 7) << 4);
        bfr[i] = *(const bf16x8*)((const char*)Bs + rb * 128 + kb);
      }
      __builtin_amdgcn_s_setprio(1);
#pragma unroll
      for (int i = 0; i < 4; ++i)
#pragma unroll
        for (int j = 0; j < 4; ++j)
          acc[i][j] = __builtin_amdgcn_mfma_f32_16x16x32_bf16(af[i], bfr[j], acc[i][j], 0, 0, 0);
      __builtin_amdgcn_s_setprio(0);
    }
  }

  if (bn_all < 20) {
    const int Hn = (bn_all < 16) ? H_ : KV_;
    bf16* C = (bn_all < 16) ? Cq : Ck;
#pragma unroll
    for (int j = 0; j < 4; ++j) {
      const int n = bn * 128 + wc * 64 + j * 16 + (lane & 15);
      const float bv = bias[n];
#pragma unroll
      for (int i = 0; i < 4; ++i) {
        const int mb = bm * 128 + wr * 64 + i * 16 + ((lane >> 4) << 2);
#pragma unroll
        for (int e = 0; e < 4; ++e) {
          const int m = mb + e;
          const float v = (acc[i][j][e] + bv) * oscale;
          const int b = m >> 11, s = m & (S_ - 1);
          const int h = n >> 6, d = n & 63;
          C[(((size_t)b * Hn + h) * S_ + s) * 64 + d] = __float2bfloat16(v);
        }
      }
    }
  } else {
    // V^T: [B,KV,D,S], lane holds 4 consecutive s -> packed 8B stores
#pragma unroll
    for (int j = 0; j < 4; ++j) {
      const int n = bn * 128 + wc * 64 + j * 16 + (lane & 15);
      const int kvh = n >> 6, d = n & 63;
      const float bv = bias[n];
#pragma unroll
      for (int i = 0; i < 4; ++i) {
        const int m0 = bm * 128 + wr * 64 + i * 16 + ((lane >> 4) << 2);
        const int b = m0 >> 11, s0 = m0 & (S_ - 1);
        bf16 t4[4];
#pragma unroll
        for (int e = 0; e < 4; ++e) t4[e] = __float2bfloat16(acc[i][j][e] + bv);
        *reinterpret_cast<uint64_t*>(
            Cv + (((size_t)b * KV_ + kvh) * D_ + d) * S_ + s0) =
            *reinterpret_cast<uint64_t*>(t4);
      }
    }
  }
}

// ---------------- output projection: out = A @ Wo^T + bo (f32 out) -------------
__global__ __launch_bounds__(256, 2) void gemm_out(
    const bf16* __restrict__ A, const bf16* __restrict__ W,
    const float* __restrict__ bias, float* __restrict__ C) {
  const int lid0 = blockIdx.y * gridDim.x + blockIdx.x;
  const int q8 = (int)(gridDim.x * gridDim.y) >> 3;
  const int lid = (lid0 & 7) * q8 + (lid0 >> 3);
  const int bm = lid & 31;   // gridDim.x == 32
  const int bn = lid >> 5;

  __shared__ __align__(16) bf16 As[128 * 64];
  __shared__ __align__(16) bf16 Bs[128 * 64];
  const int tid = threadIdx.x;
  const int lane = tid & 63, wid = tid >> 6;
  const int wr = wid >> 1, wc = wid & 1;
  const int K = HID_, N = HID_;

  f32x4 acc[4][4] = {};

  for (int k0 = 0; k0 < K; k0 += 64) {
    __syncthreads();
#pragma unroll
    for (int c = 0; c < 4; ++c) {
      const int r = c * 32 + wid * 8 + (lane >> 3);
      const int gcolb = ((lane & 7) * 16) ^ ((r & 7) << 4);
      gload_lds16(A + (size_t)(bm * 128 + r) * K + k0 + (gcolb >> 1),
                  &As[(c * 32 + wid * 8) * 64]);
      gload_lds16(W + (size_t)(bn * 128 + r) * K + k0 + (gcolb >> 1),
                  &Bs[(c * 32 + wid * 8) * 64]);
    }
    __syncthreads();
#pragma unroll
    for (int ks = 0; ks < 2; ++ks) {
      bf16x8 af[4], bfr[4];
#pragma unroll
      for (int i = 0; i < 4; ++i) {
        const int ra = wr * 64 + i * 16 + (lane & 15);
        const int ka = (ks * 64 + ((lane >> 4) << 4)) ^ ((ra & 7) << 4);
        af[i] = *(const bf16x8*)((const char*)As + ra * 128 + ka);
        const int rb = wc * 64 + i * 16 + (lane & 15);
        const int kb = (ks * 64 + ((lane >> 4) << 4)) ^ ((rb & 7) << 4);
        bfr[i] = *(const bf16x8*)((const char*)Bs + rb * 128 + kb);
      }
      __builtin_amdgcn_s_setprio(1);
#pragma unroll
      for (int i = 0; i < 4; ++i)
#pragma unroll
        for (int j = 0; j < 4; ++j)
          acc[i][j] = __builtin_amdgcn_mfma_f32_16x16x32_bf16(af[i], bfr[j], acc[i][j], 0, 0, 0);
      __builtin_amdgcn_s_setprio(0);
    }
  }

#pragma unroll
  for (int j = 0; j < 4; ++j) {
    const int n = bn * 128 + wc * 64 + j * 16 + (lane & 15);
    const float bv = bias[n];
#pragma unroll
    for (int i = 0; i < 4; ++i) {
      const int mb = bm * 128 + wr * 64 + i * 16 + ((lane >> 4) << 2);
#pragma unroll
      for (int e = 0; e < 4; ++e) {
        C[(size_t)(mb + e) * N + n] = acc[i][j][e] + bv;
      }
    }
  }
}

// ---------------- flash attention: 4 warps x 64 q-rows (2 independent 32-row
// sub-chains), swapped QK^T, 32x32 MFMA. Each K/V frag read feeds 2 MFMAs.
// Q pre-scaled by 0.125*log2e; maskL = mask*log2e; V supplied transposed
// [B,KV,D,S]. Unnormalized softmax: p = exp2(s), no max tracking.
__global__ __launch_bounds__(256, 2) void attn_fwd(
    const bf16* __restrict__ qb, const bf16* __restrict__ kb,
    const bf16* __restrict__ vtb, const float* __restrict__ maskL,
    bf16* __restrict__ ob) {
  // bijective XCD swizzle (512 blocks)
  const int lid0 = blockIdx.y * gridDim.x + blockIdx.x;
  const int q8 = (int)(gridDim.x * gridDim.y) >> 3;
  const int lid = (lid0 & 7) * q8 + (lid0 >> 3);
  const int qtile = lid & 7;      // gridDim.x == 8
  const int headid = lid >> 3;
  const int b = headid >> 5, h = headid & (H_ - 1);
  const int kv = h >> 2;
  const int tid = threadIdx.x, lane = tid & 63, wid = tid >> 6;
  const int l31 = lane & 31, hi = lane >> 5;

  __shared__ __align__(16) bf16 Ks[2][64 * 64];
  __shared__ __align__(16) bf16 VTs[2][64 * 64];  // VT[d][key], source-swizzled
  __shared__ float lsm[4][64];

  const bf16* qh = qb + ((size_t)(b * H_ + h) * S_) * D_;
  const bf16* kh = kb + ((size_t)(b * KV_ + kv) * S_) * D_;
  const bf16* vth = vtb + (size_t)(b * KV_ + kv) * D_ * S_;
  const float* mrow = maskL + (size_t)b * S_;

  // Q B-frags for 2 sub-chains: lane holds q = qs*32 + l31, d = ks*16 + hi*8 + j
  const int qrowbase = qtile * 256 + wid * 64;
  bf16x8 qf[2][4];
#pragma unroll
  for (int qs = 0; qs < 2; ++qs)
#pragma unroll
    for (int ks = 0; ks < 4; ++ks)
      qf[qs][ks] = *(const bf16x8*)(qh + (size_t)(qrowbase + qs * 32 + l31) * D_ + ks * 16 + hi * 8);

  float lp0 = 0.f, lp1 = 0.f;
  f32x16 o0[2] = {}, o1[2] = {};

  // ---- stage tile 0
#pragma unroll
  for (int c = 0; c < 2; ++c) {
    const int r = c * 32 + wid * 8 + (lane >> 3);
    const int gcolb = ((lane & 7) * 16) ^ ((r & 7) << 4);
    gload_lds16(kh + (size_t)r * D_ + (gcolb >> 1), &Ks[0][(c * 32 + wid * 8) * 64]);
    gload_lds16(vth + (size_t)r * S_ + (gcolb >> 1), &VTs[0][(c * 32 + wid * 8) * 64]);
  }
  __syncthreads();

  for (int t = 0; t < NT_; ++t) {
    const int cur = t & 1, nxt = cur ^ 1;

    // ---- prefetch tile t+1 into [nxt]
    if (t < NT_ - 1) {
#pragma unroll
      for (int c = 0; c < 2; ++c) {
        const int r = c * 32 + wid * 8 + (lane >> 3);
        const int gcolb = ((lane & 7) * 16) ^ ((r & 7) << 4);
        gload_lds16(kh + ((size_t)(t + 1) * 64 + r) * D_ + (gcolb >> 1),
                    &Ks[nxt][(c * 32 + wid * 8) * 64]);
        gload_lds16(vth + (size_t)r * S_ + (t + 1) * 64 + (gcolb >> 1),
                    &VTs[nxt][(c * 32 + wid * 8) * 64]);
      }
    }

    // ---- QK^T (swapped), C-init = maskL in C/D layout (key = e + 8*rq + 4*hi)
    f32x16 s0[2], s1[2];
#pragma unroll
    for (int kbv = 0; kbv < 2; ++kbv) {
#pragma unroll
      for (int rq = 0; rq < 4; ++rq) {
        const f32x4 m4 = *(const f32x4*)(mrow + t * 64 + kbv * 32 + rq * 8 + 4 * hi);
#pragma unroll
        for (int e = 0; e < 4; ++e) {
          s0[kbv][rq * 4 + e] = m4[e];
          s1[kbv][rq * 4 + e] = m4[e];
        }
      }
    }
#pragma unroll
    for (int kbv = 0; kbv < 2; ++kbv) {
      __builtin_amdgcn_s_setprio(1);
#pragma unroll
      for (int ks = 0; ks < 4; ++ks) {
        const int rk = kbv * 32 + l31;
        const int kbyte = (ks * 32 + hi * 16) ^ ((rk & 7) << 4);
        bf16x8 kf = *(const bf16x8*)((const char*)&Ks[cur][0] + rk * 128 + kbyte);
        s0[kbv] = __builtin_amdgcn_mfma_f32_32x32x16_bf16(kf, qf[0][ks], s0[kbv], 0, 0, 0);
        s1[kbv] = __builtin_amdgcn_mfma_f32_32x32x16_bf16(kf, qf[1][ks], s1[kbv], 0, 0, 0);
      }
      __builtin_amdgcn_s_setprio(0);
    }

    // ---- unnormalized softmax on both chains
    {
      float2 a0 = make_float2(0.f, 0.f), a1 = make_float2(0.f, 0.f);
#pragma unroll
      for (int kbv = 0; kbv < 2; ++kbv)
#pragma unroll
        for (int r8 = 0; r8 < 8; ++r8) {
          const float p00 = fexp2(s0[kbv][2 * r8]);
          const float p01 = fexp2(s0[kbv][2 * r8 + 1]);
          const float p10 = fexp2(s1[kbv][2 * r8]);
          const float p11 = fexp2(s1[kbv][2 * r8 + 1]);
          s0[kbv][2 * r8] = p00; s0[kbv][2 * r8 + 1] = p01;
          s1[kbv][2 * r8] = p10; s1[kbv][2 * r8 + 1] = p11;
          a0.x += p00; a0.y += p01;
          a1.x += p10; a1.y += p11;
        }
      lp0 += a0.x + a0.y;
      lp1 += a1.x + a1.y;
    }

    // ---- build P A-frags for both chains (cvt_pk + permlane32_swap)
    bf16x8 pa0[2][2], pa1[2][2];
#pragma unroll
    for (int kbv = 0; kbv < 2; ++kbv) {
      {
        uint32_t a0 = cvtpk_bf16(s0[kbv][0], s0[kbv][1]);
        uint32_t b0 = cvtpk_bf16(s0[kbv][4], s0[kbv][5]);
        plane32_swap(a0, b0);
        uint32_t a1 = cvtpk_bf16(s0[kbv][2], s0[kbv][3]);
        uint32_t b1 = cvtpk_bf16(s0[kbv][6], s0[kbv][7]);
        plane32_swap(a1, b1);
        i32x4 t0; t0[0] = (int)a0; t0[1] = (int)a1; t0[2] = (int)b0; t0[3] = (int)b1;
        pa0[kbv][0] = __builtin_bit_cast(bf16x8, t0);
        uint32_t a2 = cvtpk_bf16(s0[kbv][8], s0[kbv][9]);
        uint32_t b2 = cvtpk_bf16(s0[kbv][12], s0[kbv][13]);
        plane32_swap(a2, b2);
        uint32_t a3 = cvtpk_bf16(s0[kbv][10], s0[kbv][11]);
        uint32_t b3 = cvtpk_bf16(s0[kbv][14], s0[kbv][15]);
        plane32_swap(a3, b3);
        i32x4 t1; t1[0] = (int)a2; t1[1] = (int)a3; t1[2] = (int)b2; t1[3] = (int)b3;
        pa0[kbv][1] = __builtin_bit_cast(bf16x8, t1);
      }
      {
        uint32_t a0 = cvtpk_bf16(s1[kbv][0], s1[kbv][1]);
        uint32_t b0 = cvtpk_bf16(s1[kbv][4], s1[kbv][5]);
        plane32_swap(a0, b0);
        uint32_t a1 = cvtpk_bf16(s1[kbv][2], s1[kbv][3]);
        uint32_t b1 = cvtpk_bf16(s1[kbv][6], s1[kbv][7]);
        plane32_swap(a1, b1);
        i32x4 t0; t0[0] = (int)a0; t0[1] = (int)a1; t0[2] = (int)b0; t0[3] = (int)b1;
        pa1[kbv][0] = __builtin_bit_cast(bf16x8, t0);
        uint32_t a2 = cvtpk_bf16(s1[kbv][8], s1[kbv][9]);
        uint32_t b2 = cvtpk_bf16(s1[kbv][12], s1[kbv][13]);
        plane32_swap(a2, b2);
        uint32_t a3 = cvtpk_bf16(s1[kbv][10], s1[kbv][11]);
        uint32_t b3 = cvtpk_bf16(s1[kbv][14], s1[kbv][15]);
        plane32_swap(a3, b3);
        i32x4 t1; t1[0] = (int)a2; t1[1] = (int)a3; t1[2] = (int)b2; t1[3] = (int)b3;
        pa1[kbv][1] = __builtin_bit_cast(bf16x8, t1);
      }
    }

    // ---- PV: each V frag feeds both chains
#pragma unroll
    for (int db = 0; db < 2; ++db) {
      __builtin_amdgcn_s_setprio(1);
#pragma unroll
      for (int kbv = 0; kbv < 2; ++kbv)
#pragma unroll
        for (int ks2 = 0; ks2 < 2; ++ks2) {
          const int rd = db * 32 + l31;
          const int vbyte = (kbv * 64 + ks2 * 32 + hi * 16) ^ ((rd & 7) << 4);
          bf16x8 vf = *(const bf16x8*)((const char*)&VTs[cur][0] + rd * 128 + vbyte);
          o0[db] = __builtin_amdgcn_mfma_f32_32x32x16_bf16(pa0[kbv][ks2], vf, o0[db], 0, 0, 0);
          o1[db] = __builtin_amdgcn_mfma_f32_32x32x16_bf16(pa1[kbv][ks2], vf, o1[db], 0, 0, 0);
        }
      __builtin_amdgcn_s_setprio(0);
    }

    __syncthreads();  // drains prefetch + guards [cur] reuse
  }

  // ---- epilogue: row sums, redistribute to C/D layout, write
  {
    uint32_t la = __float_as_uint(lp0), lb = la;
    plane32_swap(la, lb);
    lsm[wid][l31] = __uint_as_float(la) + __uint_as_float(lb);
    uint32_t lc = __float_as_uint(lp1), ld = lc;
    plane32_swap(lc, ld);
    lsm[wid][32 + l31] = __uint_as_float(lc) + __uint_as_float(ld);
  }
  __syncthreads();
#pragma unroll
  for (int qs = 0; qs < 2; ++qs) {
#pragma unroll
    for (int rq = 0; rq < 4; ++rq) {
      const f32x4 l4 = *(const f32x4*)&lsm[wid][qs * 32 + rq * 8 + 4 * hi];
#pragma unroll
      for (int e2 = 0; e2 < 4; ++e2) {
        const float inv = 1.0f / l4[e2];
        const int q_out = e2 + 8 * rq + 4 * hi;
        const int srow = qrowbase + qs * 32 + q_out;
#pragma unroll
        for (int db = 0; db < 2; ++db) {
          const float val = (qs == 0 ? o0[db][rq * 4 + e2] : o1[db][rq * 4 + e2]) * inv;
          ob[((size_t)b * S_ + srow) * HID_ + h * 64 + db * 32 + l31] = __float2bfloat16(val);
        }
      }
    }
  }
}

extern "C" void kernel_launch(void* const* d_in, const int* in_sizes, int n_in,
                              void* d_out, int out_size, void* d_ws, size_t ws_size,
                              hipStream_t stream) {
  (void)in_sizes; (void)n_in; (void)out_size; (void)ws_size;
  const float* x  = (const float*)d_in[0];
  const float* am = (const float*)d_in[1];
  const float* Wq = (const float*)d_in[2];
  const float* bq = (const float*)d_in[3];
  const float* Wk = (const float*)d_in[4];
  const float* bk = (const float*)d_in[5];
  const float* Wv = (const float*)d_in[6];
  const float* bv = (const float*)d_in[7];
  const float* Wo = (const float*)d_in[8];
  const float* bo = (const float*)d_in[9];
  float* out = (float*)d_out;

  const size_t XE  = (size_t)B_ * S_ * HID_;
  const size_t WQE = (size_t)HID_ * HID_;
  const size_t WKE = (size_t)(KV_ * D_) * HID_;
  const size_t QE  = (size_t)B_ * H_ * S_ * D_;
  const size_t KE  = (size_t)B_ * KV_ * S_ * D_;

  bf16* xb  = (bf16*)d_ws;
  bf16* wqb = xb + XE;
  bf16* wkb = wqb + WQE;
  bf16* wvb = wkb + WKE;
  bf16* wob = wvb + WKE;
  bf16* qbuf = wob + WQE;
  bf16* kbuf = qbuf + QE;
  bf16* vtbuf = kbuf + KE;   // V^T [B,KV,D,S]
  bf16* abuf = vtbuf + KE;
  float* maskL = (float*)(abuf + XE);  // [B,S] f32

  dim3 blk(256);
  CvtJob jx  = { x,  xb,  (int)(XE / 4) };
  CvtJob jwq = { Wq, wqb, (int)(WQE / 4) };
  CvtJob jwk = { Wk, wkb, (int)(WKE / 4) };
  CvtJob jwv = { Wv, wvb, (int)(WKE / 4) };
  CvtJob jwo = { Wo, wob, (int)(WQE / 4) };
  cvt_multi<<<dim3(512, 5), blk, 0, stream>>>(jx, jwq, jwk, jwv, jwo);
  mask_prep<<<(B_ * S_ + 255) / 256, blk, 0, stream>>>(am, maskL, B_ * S_);

  const int M = B_ * S_;
  gemm_qkv<<<dim3(M / 128, 24), blk, 0, stream>>>(xb, wqb, wkb, wvb, bq, bk, bv,
                                                  qbuf, kbuf, vtbuf);
  attn_fwd<<<dim3(S_ / 256, B_ * H_), blk, 0, stream>>>(qbuf, kbuf, vtbuf, maskL, abuf);
  gemm_out<<<dim3(M / 128, HID_ / 128), blk, 0, stream>>>(abuf, wob, bo, out);
}

// Round 8
// 191.836 us; speedup vs baseline: 2.0623x; 1.0019x over previous
//
#include <hip/hip_runtime.h>
#include <hip/hip_bf16.h>
#include <stdint.h>

typedef __hip_bfloat16 bf16;
typedef __attribute__((ext_vector_type(8))) short bf16x8;
typedef __attribute__((ext_vector_type(4))) float f32x4;
typedef __attribute__((ext_vector_type(16))) float f32x16;
typedef __attribute__((ext_vector_type(4))) int i32x4;
typedef __attribute__((ext_vector_type(2))) int i32x2;

#define B_   2
#define S_   2048
#define HID_ 2048
#define H_   32
#define KV_  8
#define D_   64
#define NT_  (S_ / 64)
#define LOG2E 1.4426950408889634f

__device__ __forceinline__ void gload_lds16(const void* g, void* l) {
  __builtin_amdgcn_global_load_lds(
      (const __attribute__((address_space(1))) uint32_t*)g,
      (__attribute__((address_space(3))) uint32_t*)l, 16, 0, 0);
}
__device__ __forceinline__ float fexp2(float x) { return __builtin_amdgcn_exp2f(x); }

__device__ __forceinline__ uint32_t cvtpk_bf16(float lo, float hi) {
  uint32_t r;
  asm("v_cvt_pk_bf16_f32 %0, %1, %2" : "=v"(r) : "v"(lo), "v"(hi));
  return r;
}
__device__ __forceinline__ void plane32_swap(uint32_t& a, uint32_t& b) {
  i32x2 r = __builtin_amdgcn_permlane32_swap((int)a, (int)b, false, false);
  a = (uint32_t)r[0]; b = (uint32_t)r[1];
}

// ---- fused f32 -> bf16 conversion over 5 buffers (one launch) ----
struct CvtJob { const float* s; bf16* d; int n4; };
__global__ __launch_bounds__(256) void cvt_multi(
    CvtJob j0, CvtJob j1, CvtJob j2, CvtJob j3, CvtJob j4) {
  CvtJob j;
  switch (blockIdx.y) {
    case 0: j = j0; break;
    case 1: j = j1; break;
    case 2: j = j2; break;
    case 3: j = j3; break;
    default: j = j4; break;
  }
  int i = blockIdx.x * blockDim.x + threadIdx.x;
  const int stride = gridDim.x * blockDim.x;
  for (; i < j.n4; i += stride) {
    float4 v = ((const float4*)j.s)[i];
    bf16 t[4];
    t[0] = __float2bfloat16(v.x);
    t[1] = __float2bfloat16(v.y);
    t[2] = __float2bfloat16(v.z);
    t[3] = __float2bfloat16(v.w);
    *reinterpret_cast<uint64_t*>(j.d + 4 * (size_t)i) = *reinterpret_cast<uint64_t*>(t);
  }
}

// mask -> mask * log2e (f32)
__global__ __launch_bounds__(256) void mask_prep(
    const float* __restrict__ m, float* __restrict__ o, int n) {
  int i = blockIdx.x * blockDim.x + threadIdx.x;
  if (i < n) o[i] = m[i] * LOG2E;
}

// ---------------- fused QKV projection ----------------
// Q (scaled by 0.125*log2e) and K -> head-major [B,Hn,S,D].
// V -> transposed [B,KV,D,S]  (so attention can DMA-stage V^T directly).
__global__ __launch_bounds__(256, 3) void gemm_qkv(
    const bf16* __restrict__ A,
    const bf16* __restrict__ Wqp, const bf16* __restrict__ Wkp, const bf16* __restrict__ Wvp,
    const float* __restrict__ bqp, const float* __restrict__ bkp, const float* __restrict__ bvp,
    bf16* __restrict__ Cq, bf16* __restrict__ Ck, bf16* __restrict__ Cv) {
  const int lid0 = blockIdx.y * gridDim.x + blockIdx.x;
  const int q8 = (int)(gridDim.x * gridDim.y) >> 3;
  const int lid = (lid0 & 7) * q8 + (lid0 >> 3);
  const int bm = lid & 31;        // gridDim.x == 32
  const int bn_all = lid >> 5;

  const bf16* W; const float* bias; int bn;
  if (bn_all < 16)      { W = Wqp; bias = bqp; bn = bn_all; }
  else if (bn_all < 20) { W = Wkp; bias = bkp; bn = bn_all - 16; }
  else                  { W = Wvp; bias = bvp; bn = bn_all - 20; }
  const float oscale = (bn_all < 16) ? (0.125f * LOG2E) : 1.0f;

  __shared__ __align__(16) bf16 As[128 * 64];
  __shared__ __align__(16) bf16 Bs[128 * 64];
  const int tid = threadIdx.x;
  const int lane = tid & 63, wid = tid >> 6;
  const int wr = wid >> 1, wc = wid & 1;
  const int K = HID_;

  f32x4 acc[4][4] = {};

  for (int k0 = 0; k0 < K; k0 += 64) {
    __syncthreads();
#pragma unroll
    for (int c = 0; c < 4; ++c) {
      const int r = c * 32 + wid * 8 + (lane >> 3);
      const int gcolb = ((lane & 7) * 16) ^ ((r & 7) << 4);
      gload_lds16(A + (size_t)(bm * 128 + r) * K + k0 + (gcolb >> 1),
                  &As[(c * 32 + wid * 8) * 64]);
      gload_lds16(W + (size_t)(bn * 128 + r) * K + k0 + (gcolb >> 1),
                  &Bs[(c * 32 + wid * 8) * 64]);
    }
    __syncthreads();
#pragma unroll
    for (int ks = 0; ks < 2; ++ks) {
      bf16x8 af[4], bfr[4];
#pragma unroll
      for (int i = 0; i < 4; ++i) {
        const int ra = wr * 64 + i * 16 + (lane & 15);
        const int ka = (ks * 64 + ((lane >> 4) << 4)) ^ ((ra & 7) << 4);
        af[i] = *(const bf16x8*)((const char*)As + ra * 128 + ka);
        const int rb = wc * 64 + i * 16 + (lane & 15);
        const int kb = (ks * 64 + ((lane >> 4) << 4)) ^ ((rb & 7) << 4);
        bfr[i] = *(const bf16x8*)((const char*)Bs + rb * 128 + kb);
      }
      __builtin_amdgcn_s_setprio(1);
#pragma unroll
      for (int i = 0; i < 4; ++i)
#pragma unroll
        for (int j = 0; j < 4; ++j)
          acc[i][j] = __builtin_amdgcn_mfma_f32_16x16x32_bf16(af[i], bfr[j], acc[i][j], 0, 0, 0);
      __builtin_amdgcn_s_setprio(0);
    }
  }

  if (bn_all < 20) {
    const int Hn = (bn_all < 16) ? H_ : KV_;
    bf16* C = (bn_all < 16) ? Cq : Ck;
#pragma unroll
    for (int j = 0; j < 4; ++j) {
      const int n = bn * 128 + wc * 64 + j * 16 + (lane & 15);
      const float bv = bias[n];
#pragma unroll
      for (int i = 0; i < 4; ++i) {
        const int mb = bm * 128 + wr * 64 + i * 16 + ((lane >> 4) << 2);
#pragma unroll
        for (int e = 0; e < 4; ++e) {
          const int m = mb + e;
          const float v = (acc[i][j][e] + bv) * oscale;
          const int b = m >> 11, s = m & (S_ - 1);
          const int h = n >> 6, d = n & 63;
          C[(((size_t)b * Hn + h) * S_ + s) * 64 + d] = __float2bfloat16(v);
        }
      }
    }
  } else {
    // V^T: [B,KV,D,S], lane holds 4 consecutive s -> packed 8B stores
#pragma unroll
    for (int j = 0; j < 4; ++j) {
      const int n = bn * 128 + wc * 64 + j * 16 + (lane & 15);
      const int kvh = n >> 6, d = n & 63;
      const float bv = bias[n];
#pragma unroll
      for (int i = 0; i < 4; ++i) {
        const int m0 = bm * 128 + wr * 64 + i * 16 + ((lane >> 4) << 2);
        const int b = m0 >> 11, s0 = m0 & (S_ - 1);
        bf16 t4[4];
#pragma unroll
        for (int e = 0; e < 4; ++e) t4[e] = __float2bfloat16(acc[i][j][e] + bv);
        *reinterpret_cast<uint64_t*>(
            Cv + (((size_t)b * KV_ + kvh) * D_ + d) * S_ + s0) =
            *reinterpret_cast<uint64_t*>(t4);
      }
    }
  }
}

// ---------------- output projection: out = A @ Wo^T + bo (f32 out) -------------
__global__ __launch_bounds__(256, 2) void gemm_out(
    const bf16* __restrict__ A, const bf16* __restrict__ W,
    const float* __restrict__ bias, float* __restrict__ C) {
  const int lid0 = blockIdx.y * gridDim.x + blockIdx.x;
  const int q8 = (int)(gridDim.x * gridDim.y) >> 3;
  const int lid = (lid0 & 7) * q8 + (lid0 >> 3);
  const int bm = lid & 31;   // gridDim.x == 32
  const int bn = lid >> 5;

  __shared__ __align__(16) bf16 As[128 * 64];
  __shared__ __align__(16) bf16 Bs[128 * 64];
  const int tid = threadIdx.x;
  const int lane = tid & 63, wid = tid >> 6;
  const int wr = wid >> 1, wc = wid & 1;
  const int K = HID_, N = HID_;

  f32x4 acc[4][4] = {};

  for (int k0 = 0; k0 < K; k0 += 64) {
    __syncthreads();
#pragma unroll
    for (int c = 0; c < 4; ++c) {
      const int r = c * 32 + wid * 8 + (lane >> 3);
      const int gcolb = ((lane & 7) * 16) ^ ((r & 7) << 4);
      gload_lds16(A + (size_t)(bm * 128 + r) * K + k0 + (gcolb >> 1),
                  &As[(c * 32 + wid * 8) * 64]);
      gload_lds16(W + (size_t)(bn * 128 + r) * K + k0 + (gcolb >> 1),
                  &Bs[(c * 32 + wid * 8) * 64]);
    }
    __syncthreads();
#pragma unroll
    for (int ks = 0; ks < 2; ++ks) {
      bf16x8 af[4], bfr[4];
#pragma unroll
      for (int i = 0; i < 4; ++i) {
        const int ra = wr * 64 + i * 16 + (lane & 15);
        const int ka = (ks * 64 + ((lane >> 4) << 4)) ^ ((ra & 7) << 4);
        af[i] = *(const bf16x8*)((const char*)As + ra * 128 + ka);
        const int rb = wc * 64 + i * 16 + (lane & 15);
        const int kb = (ks * 64 + ((lane >> 4) << 4)) ^ ((rb & 7) << 4);
        bfr[i] = *(const bf16x8*)((const char*)Bs + rb * 128 + kb);
      }
      __builtin_amdgcn_s_setprio(1);
#pragma unroll
      for (int i = 0; i < 4; ++i)
#pragma unroll
        for (int j = 0; j < 4; ++j)
          acc[i][j] = __builtin_amdgcn_mfma_f32_16x16x32_bf16(af[i], bfr[j], acc[i][j], 0, 0, 0);
      __builtin_amdgcn_s_setprio(0);
    }
  }

#pragma unroll
  for (int j = 0; j < 4; ++j) {
    const int n = bn * 128 + wc * 64 + j * 16 + (lane & 15);
    const float bv = bias[n];
#pragma unroll
    for (int i = 0; i < 4; ++i) {
      const int mb = bm * 128 + wr * 64 + i * 16 + ((lane >> 4) << 2);
#pragma unroll
      for (int e = 0; e < 4; ++e) {
        C[(size_t)(mb + e) * N + n] = acc[i][j][e] + bv;
      }
    }
  }
}

// ---------------- flash attention: 4 warps x 64 q-rows (2 independent chains),
// swapped QK^T, 32x32 MFMA, pipe-overlapped emission:
//   QK(c0) -> [QK(c1) || exp2(c0)] -> [PV(c0) || exp2(c1)] -> PV(c1)
// l computed via MFMA (P @ ones) -> lands in o's C/D layout, no shuffles.
__global__ __launch_bounds__(256, 2) void attn_fwd(
    const bf16* __restrict__ qb, const bf16* __restrict__ kb,
    const bf16* __restrict__ vtb, const float* __restrict__ maskL,
    bf16* __restrict__ ob) {
  // bijective XCD swizzle (512 blocks)
  const int lid0 = blockIdx.y * gridDim.x + blockIdx.x;
  const int q8 = (int)(gridDim.x * gridDim.y) >> 3;
  const int lid = (lid0 & 7) * q8 + (lid0 >> 3);
  const int qtile = lid & 7;      // gridDim.x == 8
  const int headid = lid >> 3;
  const int b = headid >> 5, h = headid & (H_ - 1);
  const int kv = h >> 2;
  const int tid = threadIdx.x, lane = tid & 63, wid = tid >> 6;
  const int l31 = lane & 31, hi = lane >> 5;

  __shared__ __align__(16) bf16 Ks[2][64 * 64];
  __shared__ __align__(16) bf16 VTs[2][64 * 64];  // VT[d][key], source-swizzled

  const bf16* qh = qb + ((size_t)(b * H_ + h) * S_) * D_;
  const bf16* kh = kb + ((size_t)(b * KV_ + kv) * S_) * D_;
  const bf16* vth = vtb + (size_t)(b * KV_ + kv) * D_ * S_;
  const float* mrow = maskL + (size_t)b * S_;

  // Q B-frags for 2 chains: lane holds q = qs*32 + l31, d = ks*16 + hi*8 + j
  const int qrowbase = qtile * 256 + wid * 64;
  bf16x8 qf[2][4];
#pragma unroll
  for (int qs = 0; qs < 2; ++qs)
#pragma unroll
    for (int ks = 0; ks < 4; ++ks)
      qf[qs][ks] = *(const bf16x8*)(qh + (size_t)(qrowbase + qs * 32 + l31) * D_ + ks * 16 + hi * 8);

  // all-ones B-frag for l = P @ 1
  bf16x8 ones;
#pragma unroll
  for (int i = 0; i < 8; ++i) ones[i] = (short)0x3F80;

  f32x16 o0[2] = {}, o1[2] = {};
  f32x16 lacc0 = {}, lacc1 = {};

  // ---- stage tile 0
#pragma unroll
  for (int c = 0; c < 2; ++c) {
    const int r = c * 32 + wid * 8 + (lane >> 3);
    const int gcolb = ((lane & 7) * 16) ^ ((r & 7) << 4);
    gload_lds16(kh + (size_t)r * D_ + (gcolb >> 1), &Ks[0][(c * 32 + wid * 8) * 64]);
    gload_lds16(vth + (size_t)r * S_ + (gcolb >> 1), &VTs[0][(c * 32 + wid * 8) * 64]);
  }
  __syncthreads();

  for (int t = 0; t < NT_; ++t) {
    const int cur = t & 1, nxt = cur ^ 1;

    // ---- prefetch tile t+1 into [nxt]
    if (t < NT_ - 1) {
#pragma unroll
      for (int c = 0; c < 2; ++c) {
        const int r = c * 32 + wid * 8 + (lane >> 3);
        const int gcolb = ((lane & 7) * 16) ^ ((r & 7) << 4);
        gload_lds16(kh + ((size_t)(t + 1) * 64 + r) * D_ + (gcolb >> 1),
                    &Ks[nxt][(c * 32 + wid * 8) * 64]);
        gload_lds16(vth + (size_t)r * S_ + (t + 1) * 64 + (gcolb >> 1),
                    &VTs[nxt][(c * 32 + wid * 8) * 64]);
      }
    }

    // ---- mask C-init (key = (r&3) + 8*(r>>2) + 4*hi in C/D layout)
    f32x16 s0[2], s1[2];
#pragma unroll
    for (int kbv = 0; kbv < 2; ++kbv) {
#pragma unroll
      for (int rq = 0; rq < 4; ++rq) {
        const f32x4 m4 = *(const f32x4*)(mrow + t * 64 + kbv * 32 + rq * 8 + 4 * hi);
#pragma unroll
        for (int e = 0; e < 4; ++e) {
          s0[kbv][rq * 4 + e] = m4[e];
          s1[kbv][rq * 4 + e] = m4[e];
        }
      }
    }

    // ---- QK chain0 kbv0+kbv1, chain1 kbv0  (K frag reads shared)
    bf16x8 kf0[4], kf1[4];
#pragma unroll
    for (int ks = 0; ks < 4; ++ks) {
      const int rk = l31;
      const int kbyte = (ks * 32 + hi * 16) ^ ((rk & 7) << 4);
      kf0[ks] = *(const bf16x8*)((const char*)&Ks[cur][0] + rk * 128 + kbyte);
    }
    __builtin_amdgcn_s_setprio(1);
#pragma unroll
    for (int ks = 0; ks < 4; ++ks)
      s0[0] = __builtin_amdgcn_mfma_f32_32x32x16_bf16(kf0[ks], qf[0][ks], s0[0], 0, 0, 0);
#pragma unroll
    for (int ks = 0; ks < 4; ++ks)
      s1[0] = __builtin_amdgcn_mfma_f32_32x32x16_bf16(kf0[ks], qf[1][ks], s1[0], 0, 0, 0);
    __builtin_amdgcn_s_setprio(0);
#pragma unroll
    for (int ks = 0; ks < 4; ++ks) {
      const int rk = 32 + l31;
      const int kbyte = (ks * 32 + hi * 16) ^ ((rk & 7) << 4);
      kf1[ks] = *(const bf16x8*)((const char*)&Ks[cur][0] + rk * 128 + kbyte);
    }
    __builtin_amdgcn_s_setprio(1);
#pragma unroll
    for (int ks = 0; ks < 4; ++ks)
      s0[1] = __builtin_amdgcn_mfma_f32_32x32x16_bf16(kf1[ks], qf[0][ks], s0[1], 0, 0, 0);
    __builtin_amdgcn_s_setprio(0);

    // ---- softmax chain0 kbv0 (overlaps s0[1] MFMAs in the pipe)
    bf16x8 pa0[2][2], pa1[2][2];
#pragma unroll
    for (int r = 0; r < 16; ++r) s0[0][r] = fexp2(s0[0][r]);
    {
      uint32_t a0 = cvtpk_bf16(s0[0][0], s0[0][1]);
      uint32_t b0 = cvtpk_bf16(s0[0][4], s0[0][5]);
      plane32_swap(a0, b0);
      uint32_t a1 = cvtpk_bf16(s0[0][2], s0[0][3]);
      uint32_t b1 = cvtpk_bf16(s0[0][6], s0[0][7]);
      plane32_swap(a1, b1);
      i32x4 t0; t0[0] = (int)a0; t0[1] = (int)a1; t0[2] = (int)b0; t0[3] = (int)b1;
      pa0[0][0] = __builtin_bit_cast(bf16x8, t0);
      uint32_t a2 = cvtpk_bf16(s0[0][8], s0[0][9]);
      uint32_t b2 = cvtpk_bf16(s0[0][12], s0[0][13]);
      plane32_swap(a2, b2);
      uint32_t a3 = cvtpk_bf16(s0[0][10], s0[0][11]);
      uint32_t b3 = cvtpk_bf16(s0[0][14], s0[0][15]);
      plane32_swap(a3, b3);
      i32x4 t1; t1[0] = (int)a2; t1[1] = (int)a3; t1[2] = (int)b2; t1[3] = (int)b3;
      pa0[0][1] = __builtin_bit_cast(bf16x8, t1);
    }

    // ---- QK chain1 kbv1
    __builtin_amdgcn_s_setprio(1);
#pragma unroll
    for (int ks = 0; ks < 4; ++ks)
      s1[1] = __builtin_amdgcn_mfma_f32_32x32x16_bf16(kf1[ks], qf[1][ks], s1[1], 0, 0, 0);
    __builtin_amdgcn_s_setprio(0);

    // ---- softmax chain0 kbv1 (overlaps s1[1] MFMAs)
#pragma unroll
    for (int r = 0; r < 16; ++r) s0[1][r] = fexp2(s0[1][r]);
    {
      uint32_t a0 = cvtpk_bf16(s0[1][0], s0[1][1]);
      uint32_t b0 = cvtpk_bf16(s0[1][4], s0[1][5]);
      plane32_swap(a0, b0);
      uint32_t a1 = cvtpk_bf16(s0[1][2], s0[1][3]);
      uint32_t b1 = cvtpk_bf16(s0[1][6], s0[1][7]);
      plane32_swap(a1, b1);
      i32x4 t0; t0[0] = (int)a0; t0[1] = (int)a1; t0[2] = (int)b0; t0[3] = (int)b1;
      pa0[1][0] = __builtin_bit_cast(bf16x8, t0);
      uint32_t a2 = cvtpk_bf16(s0[1][8], s0[1][9]);
      uint32_t b2 = cvtpk_bf16(s0[1][12], s0[1][13]);
      plane32_swap(a2, b2);
      uint32_t a3 = cvtpk_bf16(s0[1][10], s0[1][11]);
      uint32_t b3 = cvtpk_bf16(s0[1][14], s0[1][15]);
      plane32_swap(a3, b3);
      i32x4 t1; t1[0] = (int)a2; t1[1] = (int)a3; t1[2] = (int)b2; t1[3] = (int)b3;
      pa0[1][1] = __builtin_bit_cast(bf16x8, t1);
    }

    // ---- V frags (read once, feed both chains + lacc)
    bf16x8 vf[2][4];
#pragma unroll
    for (int db = 0; db < 2; ++db)
#pragma unroll
      for (int kk = 0; kk < 4; ++kk) {
        const int kbv = kk >> 1, ks2 = kk & 1;
        const int rd = db * 32 + l31;
        const int vbyte = (kbv * 64 + ks2 * 32 + hi * 16) ^ ((rd & 7) << 4);
        vf[db][kk] = *(const bf16x8*)((const char*)&VTs[cur][0] + rd * 128 + vbyte);
      }

    // ---- l(c0) + PV(c0)  (softmax(c1) below overlaps these MFMAs)
    __builtin_amdgcn_s_setprio(1);
#pragma unroll
    for (int kk = 0; kk < 4; ++kk)
      lacc0 = __builtin_amdgcn_mfma_f32_32x32x16_bf16(pa0[kk >> 1][kk & 1], ones, lacc0, 0, 0, 0);
#pragma unroll
    for (int db = 0; db < 2; ++db)
#pragma unroll
      for (int kk = 0; kk < 4; ++kk)
        o0[db] = __builtin_amdgcn_mfma_f32_32x32x16_bf16(pa0[kk >> 1][kk & 1], vf[db][kk], o0[db], 0, 0, 0);
    __builtin_amdgcn_s_setprio(0);

    // ---- softmax chain1 (both kbv)
#pragma unroll
    for (int kbv = 0; kbv < 2; ++kbv) {
#pragma unroll
      for (int r = 0; r < 16; ++r) s1[kbv][r] = fexp2(s1[kbv][r]);
      uint32_t a0 = cvtpk_bf16(s1[kbv][0], s1[kbv][1]);
      uint32_t b0 = cvtpk_bf16(s1[kbv][4], s1[kbv][5]);
      plane32_swap(a0, b0);
      uint32_t a1 = cvtpk_bf16(s1[kbv][2], s1[kbv][3]);
      uint32_t b1 = cvtpk_bf16(s1[kbv][6], s1[kbv][7]);
      plane32_swap(a1, b1);
      i32x4 t0; t0[0] = (int)a0; t0[1] = (int)a1; t0[2] = (int)b0; t0[3] = (int)b1;
      pa1[kbv][0] = __builtin_bit_cast(bf16x8, t0);
      uint32_t a2 = cvtpk_bf16(s1[kbv][8], s1[kbv][9]);
      uint32_t b2 = cvtpk_bf16(s1[kbv][12], s1[kbv][13]);
      plane32_swap(a2, b2);
      uint32_t a3 = cvtpk_bf16(s1[kbv][10], s1[kbv][11]);
      uint32_t b3 = cvtpk_bf16(s1[kbv][14], s1[kbv][15]);
      plane32_swap(a3, b3);
      i32x4 t1; t1[0] = (int)a2; t1[1] = (int)a3; t1[2] = (int)b2; t1[3] = (int)b3;
      pa1[kbv][1] = __builtin_bit_cast(bf16x8, t1);
    }

    // ---- l(c1) + PV(c1)
    __builtin_amdgcn_s_setprio(1);
#pragma unroll
    for (int kk = 0; kk < 4; ++kk)
      lacc1 = __builtin_amdgcn_mfma_f32_32x32x16_bf16(pa1[kk >> 1][kk & 1], ones, lacc1, 0, 0, 0);
#pragma unroll
    for (int db = 0; db < 2; ++db)
#pragma unroll
      for (int kk = 0; kk < 4; ++kk)
        o1[db] = __builtin_amdgcn_mfma_f32_32x32x16_bf16(pa1[kk >> 1][kk & 1], vf[db][kk], o1[db], 0, 0, 0);
    __builtin_amdgcn_s_setprio(0);

    __syncthreads();  // drains prefetch + guards [cur] reuse
  }

  // ---- epilogue: lacc is in the SAME C/D layout as o -> direct divide
#pragma unroll
  for (int r = 0; r < 16; ++r) {
    const int q_out = (r & 3) + 8 * (r >> 2) + 4 * hi;
    {
      const float inv = 1.0f / lacc0[r];
      const int srow = qrowbase + q_out;
      ob[((size_t)b * S_ + srow) * HID_ + h * 64 + l31] = __float2bfloat16(o0[0][r] * inv);
      ob[((size_t)b * S_ + srow) * HID_ + h * 64 + 32 + l31] = __float2bfloat16(o0[1][r] * inv);
    }
    {
      const float inv = 1.0f / lacc1[r];
      const int srow = qrowbase + 32 + q_out;
      ob[((size_t)b * S_ + srow) * HID_ + h * 64 + l31] = __float2bfloat16(o1[0][r] * inv);
      ob[((size_t)b * S_ + srow) * HID_ + h * 64 + 32 + l31] = __float2bfloat16(o1[1][r] * inv);
    }
  }
}

extern "C" void kernel_launch(void* const* d_in, const int* in_sizes, int n_in,
                              void* d_out, int out_size, void* d_ws, size_t ws_size,
                              hipStream_t stream) {
  (void)in_sizes; (void)n_in; (void)out_size; (void)ws_size;
  const float* x  = (const float*)d_in[0];
  const float* am = (const float*)d_in[1];
  const float* Wq = (const float*)d_in[2];
  const float* bq = (const float*)d_in[3];
  const float* Wk = (const float*)d_in[4];
  const float* bk = (const float*)d_in[5];
  const float* Wv = (const float*)d_in[6];
  const float* bv = (const float*)d_in[7];
  const float* Wo = (const float*)d_in[8];
  const float* bo = (const float*)d_in[9];
  float* out = (float*)d_out;

  const size_t XE  = (size_t)B_ * S_ * HID_;
  const size_t WQE = (size_t)HID_ * HID_;
  const size_t WKE = (size_t)(KV_ * D_) * HID_;
  const size_t QE  = (size_t)B_ * H_ * S_ * D_;
  const size_t KE  = (size_t)B_ * KV_ * S_ * D_;

  bf16* xb  = (bf16*)d_ws;
  bf16* wqb = xb + XE;
  bf16* wkb = wqb + WQE;
  bf16* wvb = wkb + WKE;
  bf16* wob = wvb + WKE;
  bf16* qbuf = wob + WQE;
  bf16* kbuf = qbuf + QE;
  bf16* vtbuf = kbuf + KE;   // V^T [B,KV,D,S]
  bf16* abuf = vtbuf + KE;
  float* maskL = (float*)(abuf + XE);  // [B,S] f32

  dim3 blk(256);
  CvtJob jx  = { x,  xb,  (int)(XE / 4) };
  CvtJob jwq = { Wq, wqb, (int)(WQE / 4) };
  CvtJob jwk = { Wk, wkb, (int)(WKE / 4) };
  CvtJob jwv = { Wv, wvb, (int)(WKE / 4) };
  CvtJob jwo = { Wo, wob, (int)(WQE / 4) };
  cvt_multi<<<dim3(512, 5), blk, 0, stream>>>(jx, jwq, jwk, jwv, jwo);
  mask_prep<<<(B_ * S_ + 255) / 256, blk, 0, stream>>>(am, maskL, B_ * S_);

  const int M = B_ * S_;
  gemm_qkv<<<dim3(M / 128, 24), blk, 0, stream>>>(xb, wqb, wkb, wvb, bq, bk, bv,
                                                  qbuf, kbuf, vtbuf);
  attn_fwd<<<dim3(S_ / 256, B_ * H_), blk, 0, stream>>>(qbuf, kbuf, vtbuf, maskL, abuf);
  gemm_out<<<dim3(M / 128, HID_ / 128), blk, 0, stream>>>(abuf, wob, bo, out);
}